// Round 7
// baseline (4755.056 us; speedup 1.0000x reference)
//
#include <hip/hip_runtime.h>
#include <math.h>

__device__ __forceinline__ float wred_sum(float v){
  #pragma unroll
  for (int o = 32; o > 0; o >>= 1) v += __shfl_xor(v, o);
  return v;
}
__device__ __forceinline__ float wred_max(float v){
  #pragma unroll
  for (int o = 32; o > 0; o >>= 1) v = fmaxf(v, __shfl_xor(v, o));
  return v;
}
__device__ __forceinline__ float lrelu(float v){ return v > 0.f ? v : 0.2f * v; }

// ---------------- CSR build (dst-sorted) ----------------
__global__ void k_hist(const int* __restrict__ dst, int* __restrict__ deg, int E){
  int t = blockIdx.x * blockDim.x + threadIdx.x;
  if (t < E) atomicAdd(&deg[dst[t]], 1);
}

__global__ void k_deg_bsum(const int* __restrict__ deg, int* __restrict__ bsum, int n){
  __shared__ int s[256];
  int b = blockIdx.x, t = threadIdx.x;
  int i = b * 256 + t;
  s[t] = (i < n) ? deg[i] : 0;
  __syncthreads();
  for (int o = 128; o > 0; o >>= 1){ if (t < o) s[t] += s[t + o]; __syncthreads(); }
  if (t == 0) bsum[b] = s[0];
}
__global__ void k_bsum_scan(int* __restrict__ bsum, int nblk){
  __shared__ int s[256];
  int t = threadIdx.x;
  s[t] = (t < nblk) ? bsum[t] : 0;
  __syncthreads();
  for (int o = 1; o < 256; o <<= 1){
    int add = (t >= o) ? s[t - o] : 0;
    __syncthreads();
    s[t] += add;
    __syncthreads();
  }
  if (t < nblk) bsum[t] = (t > 0) ? s[t - 1] : 0;
}
__global__ void k_rowptr(const int* __restrict__ deg, const int* __restrict__ bsum,
                         int* __restrict__ rowptr, int* __restrict__ cursor, int n, int E){
  __shared__ int s[256];
  int b = blockIdx.x, t = threadIdx.x;
  int i = b * 256 + t;
  int v = (i < n) ? deg[i] : 0;
  s[t] = v;
  __syncthreads();
  for (int o = 1; o < 256; o <<= 1){
    int add = (t >= o) ? s[t - o] : 0;
    __syncthreads();
    s[t] += add;
    __syncthreads();
  }
  if (i < n){
    int rp = bsum[b] + s[t] - v;
    rowptr[i] = rp;
    cursor[i] = rp;
    if (i == n - 1) rowptr[n] = E;
  }
}

__global__ void k_scatter(const int* __restrict__ src, const int* __restrict__ dst,
                          int* __restrict__ cursor, int* __restrict__ esrc, int E){
  int t = blockIdx.x * blockDim.x + threadIdx.x;
  if (t < E){
    int d = dst[t];
    int p = atomicAdd(&cursor[d], 1);
    esrc[p] = src[t];
  }
}

// ---------------- attention-logit weight precompute: vv = W^T {al, ar} ----------------
__global__ void k_valvar_all(const float* __restrict__ W1, const float* __restrict__ al1, const float* __restrict__ ar1,
                             const float* __restrict__ W2, const float* __restrict__ al2, const float* __restrict__ ar2,
                             const float* __restrict__ Wm, const float* __restrict__ alm, const float* __restrict__ arm,
                             float* __restrict__ vv1, float* __restrict__ vv2, float* __restrict__ vvm){
  int b = blockIdx.x, k = threadIdx.x;
  if (b == 0){
    if (k < 64){ // L1: K=64, C=128, H=1
      float v = 0.f, w = 0.f;
      for (int c = 0; c < 128; c++){ float ww = W1[c * 64 + k]; v += al1[c] * ww; w += ar1[c] * ww; }
      vv1[k] = v; vv1[64 + k] = w;
    }
  } else if (b == 1){ // L2: K=128, C=64, H=1
    float v = 0.f, w = 0.f;
    for (int c = 0; c < 64; c++){ float ww = W2[c * 128 + k]; v += al2[c] * ww; w += ar2[c] * ww; }
    vv2[k] = v; vv2[128 + k] = w;
  } else {
    if (k < 64){ // MH: K=64, C=256, H=4
      for (int h = 0; h < 4; h++){
        float v = 0.f, w = 0.f;
        for (int c = 0; c < 64; c++){
          float ww = Wm[(size_t)(h * 64 + c) * 64 + k];
          v += alm[h * 64 + c] * ww; w += arm[h * 64 + c] * ww;
        }
        vvm[(2 * h) * 64 + k] = v; vvm[(2 * h + 1) * 64 + k] = w;
      }
    }
  }
}

// ---------------- fused dual GEMM, 2 column-chunks per pass ----------------
// __launch_bounds__(256,3): LDS caps at 3 blocks/CU anyway; raise VGPR cap to ~168
// so the 4-row-batched inner loop can keep ~60 independent values in flight
// (prevents the 64-VGPR ILP collapse measured in r6: VALUBusy 47%, dur 126us).
template<int K, int C, int H>
__global__ void __launch_bounds__(256, 3)
k_gemm2(const float* __restrict__ x,
        const float* __restrict__ Wa, const float* __restrict__ Wb,
        const float* __restrict__ vv,
        float* __restrict__ za, float* __restrict__ zb,
        float* __restrict__ el, float* __restrict__ er, int n){
  constexpr int K4 = K / 4, NKC = K / 64, NCC = C / 64;
  constexpr int ROWS = 16384 / (K * 4);
  constexpr int RPW = ROWS / 4;
  constexpr int NP = NCC;           // (2*NCC chunks) / 2
  __shared__ float  XS[ROWS][K];
  __shared__ float4 WQ[2][16 * 65];

  int t = threadIdx.x, lane = t & 63, wv = t >> 6;
  int rowbase = blockIdx.x * ROWS;

  for (int idx = t; idx < ROWS * K4; idx += 256){
    int r = idx / K4, k4 = idx - r * K4;
    int row = rowbase + r;
    float4 v = make_float4(0.f, 0.f, 0.f, 0.f);
    if (row < n) v = *(const float4*)&x[(size_t)row * K + k4 * 4];
    *(float4*)&XS[r][k4 * 4] = v;
  }

  const int r0 = wv * RPW;
  float acc0[RPW], acc1[RPW];

  for (int p = 0; p < NP; p++){
    int q0 = 2 * p, q1 = q0 + 1;
    const float* Wp0 = (q0 < NCC) ? (Wa + (size_t)q0 * 64 * K) : (Wb + (size_t)(q0 - NCC) * 64 * K);
    const float* Wp1 = (q1 < NCC) ? (Wa + (size_t)q1 * 64 * K) : (Wb + (size_t)(q1 - NCC) * 64 * K);
    #pragma unroll
    for (int r = 0; r < RPW; r++){ acc0[r] = 0.f; acc1[r] = 0.f; }

    for (int kc = 0; kc < NKC; kc++){
      __syncthreads();
      const float4* A4 = (const float4*)Wp0;
      const float4* B4 = (const float4*)Wp1;
      for (int idx = t; idx < 1024; idx += 256){
        int c = idx >> 4, k4 = idx & 15;
        WQ[0][k4 * 65 + c] = A4[(size_t)c * K4 + kc * 16 + k4];
        WQ[1][k4 * 65 + c] = B4[(size_t)c * K4 + kc * 16 + k4];
      }
      __syncthreads();
      #pragma unroll
      for (int k4 = 0; k4 < 16; k4++){
        float4 w0 = WQ[0][k4 * 65 + lane];
        float4 w1 = WQ[1][k4 * 65 + lane];
        #pragma unroll
        for (int rb = 0; rb < RPW; rb += 4){
          float4 xa = *(const float4*)&XS[r0 + rb + 0][kc * 64 + k4 * 4];
          float4 xb = *(const float4*)&XS[r0 + rb + 1][kc * 64 + k4 * 4];
          float4 xc = *(const float4*)&XS[r0 + rb + 2][kc * 64 + k4 * 4];
          float4 xd = *(const float4*)&XS[r0 + rb + 3][kc * 64 + k4 * 4];
          acc0[rb + 0] += xa.x * w0.x + xa.y * w0.y + xa.z * w0.z + xa.w * w0.w;
          acc1[rb + 0] += xa.x * w1.x + xa.y * w1.y + xa.z * w1.z + xa.w * w1.w;
          acc0[rb + 1] += xb.x * w0.x + xb.y * w0.y + xb.z * w0.z + xb.w * w0.w;
          acc1[rb + 1] += xb.x * w1.x + xb.y * w1.y + xb.z * w1.z + xb.w * w1.w;
          acc0[rb + 2] += xc.x * w0.x + xc.y * w0.y + xc.z * w0.z + xc.w * w0.w;
          acc1[rb + 2] += xc.x * w1.x + xc.y * w1.y + xc.z * w1.z + xc.w * w1.w;
          acc0[rb + 3] += xd.x * w0.x + xd.y * w0.y + xd.z * w0.z + xd.w * w0.w;
          acc1[rb + 3] += xd.x * w1.x + xd.y * w1.y + xd.z * w1.z + xd.w * w1.w;
        }
      }
    }

    float* z0 = (q0 < NCC) ? za : zb;
    float* z1 = (q1 < NCC) ? za : zb;
    int c0 = ((q0 < NCC) ? q0 : q0 - NCC) * 64;
    int c1 = ((q1 < NCC) ? q1 : q1 - NCC) * 64;
    #pragma unroll
    for (int r = 0; r < RPW; r++){
      int row = rowbase + r0 + r;
      if (row < n){
        z0[(size_t)row * C + c0 + lane] = acc0[r];
        z1[(size_t)row * C + c1 + lane] = acc1[r];
      }
    }
  }

  // ext chunk: cols 0..2H-1 of vv -> el/er (lanes >= 2H compute garbage, unwritten)
  {
    #pragma unroll
    for (int r = 0; r < RPW; r++) acc0[r] = 0.f;
    for (int kc = 0; kc < NKC; kc++){
      __syncthreads();
      const float4* V4 = (const float4*)vv;
      for (int idx = t; idx < 2 * H * 16; idx += 256){
        int c = idx >> 4, k4 = idx & 15;
        WQ[0][k4 * 65 + c] = V4[(size_t)c * K4 + kc * 16 + k4];
      }
      __syncthreads();
      #pragma unroll
      for (int k4 = 0; k4 < 16; k4++){
        float4 w0 = WQ[0][k4 * 65 + lane];
        #pragma unroll
        for (int rb = 0; rb < RPW; rb += 4){
          float4 xa = *(const float4*)&XS[r0 + rb + 0][kc * 64 + k4 * 4];
          float4 xb = *(const float4*)&XS[r0 + rb + 1][kc * 64 + k4 * 4];
          float4 xc = *(const float4*)&XS[r0 + rb + 2][kc * 64 + k4 * 4];
          float4 xd = *(const float4*)&XS[r0 + rb + 3][kc * 64 + k4 * 4];
          acc0[rb + 0] += xa.x * w0.x + xa.y * w0.y + xa.z * w0.z + xa.w * w0.w;
          acc0[rb + 1] += xb.x * w0.x + xb.y * w0.y + xb.z * w0.z + xb.w * w0.w;
          acc0[rb + 2] += xc.x * w0.x + xc.y * w0.y + xc.z * w0.z + xc.w * w0.w;
          acc0[rb + 3] += xd.x * w0.x + xd.y * w0.y + xd.z * w0.z + xd.w * w0.w;
        }
      }
    }
    if (lane < 2 * H){
      int h = lane >> 1;
      float* dst = (lane & 1) ? er : el;
      #pragma unroll
      for (int r = 0; r < RPW; r++){
        int row = rowbase + r0 + r;
        if (row < n) dst[(size_t)row * H + h] = acc0[r];
      }
    }
  }
}

// ---------------- GAT aggregation, 1 head, fused with chain-shift + mean ----------------
template<int D>
__global__ void k_gat_h1(const int* __restrict__ rowptr, const int* __restrict__ esrc,
                         const float* __restrict__ z, const float* __restrict__ el,
                         const float* __restrict__ er, const float* __restrict__ b,
                         const float* __restrict__ zb, const float* __restrict__ bb,
                         float* __restrict__ out, int n){
  constexpr int DR = D / 64;
  int lane = threadIdx.x & 63;
  int i = blockIdx.x * (blockDim.x >> 6) + (threadIdx.x >> 6);
  if (i >= n) return;
  int s0 = rowptr[i], s1 = rowptr[i + 1];
  float eri = er[i];
  float m = -INFINITY;
  for (int e = s0 + lane; e < s1; e += 64)
    m = fmaxf(m, lrelu(el[esrc[e]] + eri));
  m = wred_max(m);
  float den = 0.f, den2 = 0.f;
  float acc[DR], acc2[DR];
  #pragma unroll
  for (int j = 0; j < DR; j++){ acc[j] = 0.f; acc2[j] = 0.f; }
  int e = s0;
  for (; e + 1 < s1; e += 2){
    int sA = esrc[e], sB = esrc[e + 1];
    float wA = __expf(lrelu(el[sA] + eri) - m);
    float wB = __expf(lrelu(el[sB] + eri) - m);
    den += wA; den2 += wB;
    const float* zA = z + (size_t)sA * D;
    const float* zB = z + (size_t)sB * D;
    #pragma unroll
    for (int j = 0; j < DR; j++){
      acc[j]  += wA * zA[j * 64 + lane];
      acc2[j] += wB * zB[j * 64 + lane];
    }
  }
  if (e < s1){
    int sA = esrc[e];
    float wA = __expf(lrelu(el[sA] + eri) - m);
    den += wA;
    const float* zA = z + (size_t)sA * D;
    #pragma unroll
    for (int j = 0; j < DR; j++) acc[j] += wA * zA[j * 64 + lane];
  }
  den += den2;
  float inv = (s1 > s0) ? 1.f / den : 0.f;
  float* op = out + (size_t)i * D;
  #pragma unroll
  for (int j = 0; j < DR; j++){
    int c = j * 64 + lane;
    float chain = bb[c];
    if (i > 0) chain += zb[(size_t)(i - 1) * D + c];
    op[c] = 0.5f * (((acc[j] + acc2[j]) * inv + b[c]) + chain);
  }
}

// ---------------- GAT aggregation, 4 heads x 64 dims ----------------
__global__ void k_gat_mh(const int* __restrict__ rowptr, const int* __restrict__ esrc,
                         const float* __restrict__ z, const float* __restrict__ el,
                         const float* __restrict__ er, const float* __restrict__ b,
                         const float* __restrict__ zb, const float* __restrict__ bb,
                         float* __restrict__ out, int n){
  int lane = threadIdx.x & 63;
  int i = blockIdx.x * (blockDim.x >> 6) + (threadIdx.x >> 6);
  if (i >= n) return;
  int s0 = rowptr[i], s1 = rowptr[i + 1];
  const float4 eri = *(const float4*)(er + (size_t)i * 4);
  float m0 = -INFINITY, m1 = -INFINITY, m2 = -INFINITY, m3 = -INFINITY;
  for (int e = s0 + lane; e < s1; e += 64){
    float4 e4 = *(const float4*)(el + (size_t)esrc[e] * 4);
    m0 = fmaxf(m0, lrelu(e4.x + eri.x));
    m1 = fmaxf(m1, lrelu(e4.y + eri.y));
    m2 = fmaxf(m2, lrelu(e4.z + eri.z));
    m3 = fmaxf(m3, lrelu(e4.w + eri.w));
  }
  m0 = wred_max(m0); m1 = wred_max(m1); m2 = wred_max(m2); m3 = wred_max(m3);
  float d0 = 0.f, d1 = 0.f, d2 = 0.f, d3 = 0.f;
  float a0 = 0.f, a1 = 0.f, a2 = 0.f, a3 = 0.f;
  float d0B = 0.f, d1B = 0.f, d2B = 0.f, d3B = 0.f;
  float a0B = 0.f, a1B = 0.f, a2B = 0.f, a3B = 0.f;
  int e = s0;
  for (; e + 1 < s1; e += 2){
    int sA = esrc[e], sB = esrc[e + 1];
    float4 eA = *(const float4*)(el + (size_t)sA * 4);
    float4 eB = *(const float4*)(el + (size_t)sB * 4);
    const float* zA = z + (size_t)sA * 256;
    const float* zB = z + (size_t)sB * 256;
    float w0 = __expf(lrelu(eA.x + eri.x) - m0);
    float w1 = __expf(lrelu(eA.y + eri.y) - m1);
    float w2 = __expf(lrelu(eA.z + eri.z) - m2);
    float w3 = __expf(lrelu(eA.w + eri.w) - m3);
    float v0 = __expf(lrelu(eB.x + eri.x) - m0);
    float v1 = __expf(lrelu(eB.y + eri.y) - m1);
    float v2 = __expf(lrelu(eB.z + eri.z) - m2);
    float v3 = __expf(lrelu(eB.w + eri.w) - m3);
    d0 += w0; d1 += w1; d2 += w2; d3 += w3;
    d0B += v0; d1B += v1; d2B += v2; d3B += v3;
    a0 += w0 * zA[lane];        a0B += v0 * zB[lane];
    a1 += w1 * zA[64 + lane];   a1B += v1 * zB[64 + lane];
    a2 += w2 * zA[128 + lane];  a2B += v2 * zB[128 + lane];
    a3 += w3 * zA[192 + lane];  a3B += v3 * zB[192 + lane];
  }
  if (e < s1){
    int sA = esrc[e];
    float4 eA = *(const float4*)(el + (size_t)sA * 4);
    const float* zA = z + (size_t)sA * 256;
    float w0 = __expf(lrelu(eA.x + eri.x) - m0);
    float w1 = __expf(lrelu(eA.y + eri.y) - m1);
    float w2 = __expf(lrelu(eA.z + eri.z) - m2);
    float w3 = __expf(lrelu(eA.w + eri.w) - m3);
    d0 += w0; d1 += w1; d2 += w2; d3 += w3;
    a0 += w0 * zA[lane];
    a1 += w1 * zA[64 + lane];
    a2 += w2 * zA[128 + lane];
    a3 += w3 * zA[192 + lane];
  }
  d0 += d0B; d1 += d1B; d2 += d2B; d3 += d3B;
  a0 += a0B; a1 += a1B; a2 += a2B; a3 += a3B;
  float has = (s1 > s0) ? 1.f : 0.f;
  a0 = (has != 0.f) ? a0 / d0 : 0.f;
  a1 = (has != 0.f) ? a1 / d1 : 0.f;
  a2 = (has != 0.f) ? a2 / d2 : 0.f;
  a3 = (has != 0.f) ? a3 / d3 : 0.f;
  float* op = out + (size_t)i * 256;
  float av[4] = {a0, a1, a2, a3};
  #pragma unroll
  for (int h = 0; h < 4; h++){
    int c = h * 64 + lane;
    float chain = bb[c];
    if (i > 0) chain += zb[(size_t)(i - 1) * 256 + c];
    op[c] = 0.5f * ((av[h] + b[c]) + chain);
  }
}

// ---------------- chain_pass ----------------
__global__ void k_chainpass64(const float* __restrict__ h, float* __restrict__ dh, int n){
  int lane = threadIdx.x & 63;
  int i = blockIdx.x * (blockDim.x >> 6) + (threadIdx.x >> 6);
  if (i >= n) return;
  float d = 0.f;
  if (i > 0) d = h[(size_t)(i - 1) * 64 + lane] - h[(size_t)i * 64 + lane];
  float ss = wred_sum(d * d);
  dh[(size_t)i * 64 + lane] = d / (sqrtf(ss) + 1e-7f);
}

__global__ void k_chainpass_mh(const float* __restrict__ hm, float* __restrict__ ds, int n){
  int lane = threadIdx.x & 63;
  int i = blockIdx.x * (blockDim.x >> 6) + (threadIdx.x >> 6);
  if (i >= n) return;
  const float* cur = hm + (size_t)i * 256;
  const float* prv = hm + (size_t)(i - 1) * 256;
  #pragma unroll
  for (int h = 0; h < 4; h++){
    int c = h * 64 + lane;
    float d = (i > 0) ? (prv[c] - cur[c]) : 0.f;
    float ss = wred_sum(d * d);
    ds[(size_t)i * 256 + c] = d / (sqrtf(ss) + 1e-7f);
  }
}

// ---------------- column-wise prefix sum over nodes (256 cols) ----------------
__global__ void k_chunk_sum(const float* __restrict__ ds, float* __restrict__ csum, int n, int ch){
  int b = blockIdx.x, t = threadIdx.x;
  int r0 = b * ch, r1 = r0 + ch; if (r1 > n) r1 = n;
  float s = 0.f;
  for (int r = r0; r < r1; r++) s += ds[(size_t)r * 256 + t];
  csum[(size_t)b * 256 + t] = s;
}
__global__ void k_scan_chunks_par(float* __restrict__ csum, int nb){
  __shared__ float s[512];
  int col = blockIdx.x;
  int t = threadIdx.x;
  s[t] = (t < nb) ? csum[(size_t)t * 256 + col] : 0.f;
  __syncthreads();
  #pragma unroll
  for (int o = 1; o < 512; o <<= 1){
    float add = (t >= o) ? s[t - o] : 0.f;
    __syncthreads();
    s[t] += add;
    __syncthreads();
  }
  if (t < nb) csum[(size_t)t * 256 + col] = (t > 0) ? s[t - 1] : 0.f;
}
__global__ void k_apply_scan(float* __restrict__ ds, const float* __restrict__ csum, int n, int ch){
  int b = blockIdx.x, t = threadIdx.x;
  int r0 = b * ch, r1 = r0 + ch; if (r1 > n) r1 = n;
  float run = csum[(size_t)b * 256 + t];
  for (int r = r0; r < r1; r++){
    run += ds[(size_t)r * 256 + t];
    ds[(size_t)r * 256 + t] = run;
  }
}

extern "C" void kernel_launch(void* const* d_in, const int* in_sizes, int n_in,
                              void* d_out, int out_size, void* d_ws, size_t ws_size,
                              hipStream_t stream){
  const float* x    = (const float*)d_in[0];
  const int*   src0 = (const int*)d_in[1];
  const int*   dst0 = (const int*)d_in[2];
  const float* W1a  = (const float*)d_in[5];
  const float* al1a = (const float*)d_in[6];
  const float* ar1a = (const float*)d_in[7];
  const float* b1a  = (const float*)d_in[8];
  const float* W1b  = (const float*)d_in[9];
  const float* b1b  = (const float*)d_in[12];
  const float* W2a  = (const float*)d_in[13];
  const float* al2a = (const float*)d_in[14];
  const float* ar2a = (const float*)d_in[15];
  const float* b2a  = (const float*)d_in[16];
  const float* W2b  = (const float*)d_in[17];
  const float* b2b  = (const float*)d_in[20];
  const float* Wma  = (const float*)d_in[21];
  const float* alma = (const float*)d_in[22];
  const float* arma = (const float*)d_in[23];
  const float* bma  = (const float*)d_in[24];
  const float* Wmb  = (const float*)d_in[25];
  const float* bmb  = (const float*)d_in[28];

  const int n = in_sizes[0] / 64;
  const int E = in_sizes[1];
  const size_t nf = (size_t)n;

  float* ws  = (float*)d_ws;
  float* A   = ws;
  float* B   = A + nf * 256;
  float* C   = B + nf * 256;
  float* D2  = C + nf * 256;   // h2 [n,64]
  float* E2  = D2 + nf * 64;   // dh [n,64]
  float* ela = E2 + nf * 64;   // [n,4]
  float* era = ela + nf * 4;
  const int ch = 100;
  const int nb = (n + ch - 1) / ch;      // 500 <= 512
  float* csum = era + nf * 4;  // [nb,256]
  int* deg    = (int*)(csum + (size_t)nb * 256);
  int* rowptr = deg + n;
  int* cursor = rowptr + (n + 1);
  int* esrc   = cursor + n;
  int* bsum   = esrc + E;
  float* vv1  = (float*)(bsum + 256);  // [2][64]
  float* vv2  = vv1 + 128;             // [2][128]
  float* vvm  = vv2 + 256;             // [8][64]

  float* dsout = (float*)d_out;

  const int nwb  = (n + 3) / 4;
  const int eb   = (E + 255) / 256;
  const int nblk = (n + 255) / 256;

  // CSR of interacts graph by dst (shared by all three GAT layers)
  hipMemsetAsync(deg, 0, (size_t)n * sizeof(int), stream);
  k_hist<<<eb, 256, 0, stream>>>(dst0, deg, E);
  k_deg_bsum<<<nblk, 256, 0, stream>>>(deg, bsum, n);
  k_bsum_scan<<<1, 256, 0, stream>>>(bsum, nblk);
  k_rowptr<<<nblk, 256, 0, stream>>>(deg, bsum, rowptr, cursor, n, E);
  k_scatter<<<eb, 256, 0, stream>>>(src0, dst0, cursor, esrc, E);

  // attention logit vectors
  k_valvar_all<<<3, 128, 0, stream>>>(W1a, al1a, ar1a, W2a, al2a, ar2a, Wma, alma, arma,
                                      vv1, vv2, vvm);

  // layer 1: in=64 -> hid=128 (a+b fused)
  k_gemm2<64, 128, 1><<<(n + 63) / 64, 256, 0, stream>>>(x, W1a, W1b, vv1, A, B, ela, era, n);
  k_gat_h1<128><<<nwb, 256, 0, stream>>>(rowptr, esrc, A, ela, era, b1a, B, b1b, C, n);

  // layer 2: hid=128 -> out=64 (a+b fused)
  k_gemm2<128, 64, 1><<<(n + 31) / 32, 256, 0, stream>>>(C, W2a, W2b, vv2, A, B, ela, era, n);
  k_gat_h1<64><<<nwb, 256, 0, stream>>>(rowptr, esrc, A, ela, era, b2a, B, b2b, D2, n);

  // dh = chain_pass(h2)
  k_chainpass64<<<nwb, 256, 0, stream>>>(D2, E2, n);

  // MH layer: out=64 -> 4 heads x 64 (a+b fused)
  k_gemm2<64, 256, 4><<<(n + 63) / 64, 256, 0, stream>>>(E2, Wma, Wmb, vvm, A, B, ela, era, n);
  k_gat_mh<<<nwb, 256, 0, stream>>>(rowptr, esrc, A, ela, era, bma, B, bmb, C, n);

  // ds = chain_pass(hm) -> staged directly in d_out
  k_chainpass_mh<<<nwb, 256, 0, stream>>>(C, dsout, n);

  // res = cumsum(ds, axis=0), in-place in d_out
  k_chunk_sum<<<nb, 256, 0, stream>>>(dsout, csum, n, ch);
  k_scan_chunks_par<<<256, 512, 0, stream>>>(csum, nb);
  k_apply_scan<<<nb, 256, 0, stream>>>(dsout, csum, n, ch);
}

// Round 8
// 692.157 us; speedup vs baseline: 6.8699x; 6.8699x over previous
//
#include <hip/hip_runtime.h>
#include <math.h>

__device__ __forceinline__ float wred_sum(float v){
  #pragma unroll
  for (int o = 32; o > 0; o >>= 1) v += __shfl_xor(v, o);
  return v;
}
__device__ __forceinline__ float wred_max(float v){
  #pragma unroll
  for (int o = 32; o > 0; o >>= 1) v = fmaxf(v, __shfl_xor(v, o));
  return v;
}
__device__ __forceinline__ float lrelu(float v){ return v > 0.f ? v : 0.2f * v; }
__device__ __forceinline__ float sel4(int h, float4 v){
  return (h & 2) ? ((h & 1) ? v.w : v.z) : ((h & 1) ? v.y : v.x);
}

// ---------------- CSR build (dst-sorted) ----------------
__global__ void k_hist(const int* __restrict__ dst, int* __restrict__ deg, int E){
  int t = blockIdx.x * blockDim.x + threadIdx.x;
  if (t < E) atomicAdd(&deg[dst[t]], 1);
}

__global__ void k_deg_bsum(const int* __restrict__ deg, int* __restrict__ bsum, int n){
  __shared__ int s[256];
  int b = blockIdx.x, t = threadIdx.x;
  int i = b * 256 + t;
  s[t] = (i < n) ? deg[i] : 0;
  __syncthreads();
  for (int o = 128; o > 0; o >>= 1){ if (t < o) s[t] += s[t + o]; __syncthreads(); }
  if (t == 0) bsum[b] = s[0];
}
__global__ void k_bsum_scan(int* __restrict__ bsum, int nblk){
  __shared__ int s[256];
  int t = threadIdx.x;
  s[t] = (t < nblk) ? bsum[t] : 0;
  __syncthreads();
  for (int o = 1; o < 256; o <<= 1){
    int add = (t >= o) ? s[t - o] : 0;
    __syncthreads();
    s[t] += add;
    __syncthreads();
  }
  if (t < nblk) bsum[t] = (t > 0) ? s[t - 1] : 0;
}
__global__ void k_rowptr(const int* __restrict__ deg, const int* __restrict__ bsum,
                         int* __restrict__ rowptr, int* __restrict__ cursor, int n, int E){
  __shared__ int s[256];
  int b = blockIdx.x, t = threadIdx.x;
  int i = b * 256 + t;
  int v = (i < n) ? deg[i] : 0;
  s[t] = v;
  __syncthreads();
  for (int o = 1; o < 256; o <<= 1){
    int add = (t >= o) ? s[t - o] : 0;
    __syncthreads();
    s[t] += add;
    __syncthreads();
  }
  if (i < n){
    int rp = bsum[b] + s[t] - v;
    rowptr[i] = rp;
    cursor[i] = rp;
    if (i == n - 1) rowptr[n] = E;
  }
}

__global__ void k_scatter(const int* __restrict__ src, const int* __restrict__ dst,
                          int* __restrict__ cursor, int* __restrict__ esrc, int E){
  int t = blockIdx.x * blockDim.x + threadIdx.x;
  if (t < E){
    int d = dst[t];
    int p = atomicAdd(&cursor[d], 1);
    esrc[p] = src[t];
  }
}

// ---------------- attention-logit weight precompute: vv = W^T {al, ar} ----------------
__global__ void k_valvar_all(const float* __restrict__ W1, const float* __restrict__ al1, const float* __restrict__ ar1,
                             const float* __restrict__ W2, const float* __restrict__ al2, const float* __restrict__ ar2,
                             const float* __restrict__ Wm, const float* __restrict__ alm, const float* __restrict__ arm,
                             float* __restrict__ vv1, float* __restrict__ vv2, float* __restrict__ vvm){
  int b = blockIdx.x, k = threadIdx.x;
  if (b == 0){
    if (k < 64){ // L1: K=64, C=128, H=1
      float v = 0.f, w = 0.f;
      for (int c = 0; c < 128; c++){ float ww = W1[c * 64 + k]; v += al1[c] * ww; w += ar1[c] * ww; }
      vv1[k] = v; vv1[64 + k] = w;
    }
  } else if (b == 1){ // L2: K=128, C=64, H=1
    float v = 0.f, w = 0.f;
    for (int c = 0; c < 64; c++){ float ww = W2[c * 128 + k]; v += al2[c] * ww; w += ar2[c] * ww; }
    vv2[k] = v; vv2[128 + k] = w;
  } else {
    if (k < 64){ // MH: K=64, C=256, H=4
      for (int h = 0; h < 4; h++){
        float v = 0.f, w = 0.f;
        for (int c = 0; c < 64; c++){
          float ww = Wm[(size_t)(h * 64 + c) * 64 + k];
          v += alm[h * 64 + c] * ww; w += arm[h * 64 + c] * ww;
        }
        vvm[(2 * h) * 64 + k] = v; vvm[(2 * h + 1) * 64 + k] = w;
      }
    }
  }
}

// ---------------- fused dual GEMM, 2 column-chunks per pass (r6 body, measured) ----------------
template<int K, int C, int H>
__global__ void k_gemm2(const float* __restrict__ x,
                        const float* __restrict__ Wa, const float* __restrict__ Wb,
                        const float* __restrict__ vv,
                        float* __restrict__ za, float* __restrict__ zb,
                        float* __restrict__ el, float* __restrict__ er, int n){
  constexpr int K4 = K / 4, NKC = K / 64, NCC = C / 64;
  constexpr int ROWS = 16384 / (K * 4);
  constexpr int RPW = ROWS / 4;
  constexpr int NP = NCC;
  __shared__ float  XS[ROWS][K];
  __shared__ float4 WQ[2][16 * 65];

  int t = threadIdx.x, lane = t & 63, wv = t >> 6;
  int rowbase = blockIdx.x * ROWS;

  for (int idx = t; idx < ROWS * K4; idx += 256){
    int r = idx / K4, k4 = idx - r * K4;
    int row = rowbase + r;
    float4 v = make_float4(0.f, 0.f, 0.f, 0.f);
    if (row < n) v = *(const float4*)&x[(size_t)row * K + k4 * 4];
    *(float4*)&XS[r][k4 * 4] = v;
  }

  const int r0 = wv * RPW;
  float acc0[RPW], acc1[RPW];

  for (int p = 0; p < NP; p++){
    int q0 = 2 * p, q1 = q0 + 1;
    const float* Wp0 = (q0 < NCC) ? (Wa + (size_t)q0 * 64 * K) : (Wb + (size_t)(q0 - NCC) * 64 * K);
    const float* Wp1 = (q1 < NCC) ? (Wa + (size_t)q1 * 64 * K) : (Wb + (size_t)(q1 - NCC) * 64 * K);
    #pragma unroll
    for (int r = 0; r < RPW; r++){ acc0[r] = 0.f; acc1[r] = 0.f; }

    for (int kc = 0; kc < NKC; kc++){
      __syncthreads();
      const float4* A4 = (const float4*)Wp0;
      const float4* B4 = (const float4*)Wp1;
      for (int idx = t; idx < 1024; idx += 256){
        int c = idx >> 4, k4 = idx & 15;
        WQ[0][k4 * 65 + c] = A4[(size_t)c * K4 + kc * 16 + k4];
        WQ[1][k4 * 65 + c] = B4[(size_t)c * K4 + kc * 16 + k4];
      }
      __syncthreads();
      #pragma unroll 4
      for (int k4 = 0; k4 < 16; k4++){
        float4 w0 = WQ[0][k4 * 65 + lane];
        float4 w1 = WQ[1][k4 * 65 + lane];
        #pragma unroll
        for (int r = 0; r < RPW; r++){
          float4 xk = *(const float4*)&XS[r0 + r][kc * 64 + k4 * 4];
          acc0[r] += xk.x * w0.x + xk.y * w0.y + xk.z * w0.z + xk.w * w0.w;
          acc1[r] += xk.x * w1.x + xk.y * w1.y + xk.z * w1.z + xk.w * w1.w;
        }
      }
    }

    float* z0 = (q0 < NCC) ? za : zb;
    float* z1 = (q1 < NCC) ? za : zb;
    int c0 = ((q0 < NCC) ? q0 : q0 - NCC) * 64;
    int c1 = ((q1 < NCC) ? q1 : q1 - NCC) * 64;
    #pragma unroll
    for (int r = 0; r < RPW; r++){
      int row = rowbase + r0 + r;
      if (row < n){
        z0[(size_t)row * C + c0 + lane] = acc0[r];
        z1[(size_t)row * C + c1 + lane] = acc1[r];
      }
    }
  }

  // ext chunk: cols 0..2H-1 of vv -> el/er
  {
    #pragma unroll
    for (int r = 0; r < RPW; r++) acc0[r] = 0.f;
    for (int kc = 0; kc < NKC; kc++){
      __syncthreads();
      const float4* V4 = (const float4*)vv;
      for (int idx = t; idx < 2 * H * 16; idx += 256){
        int c = idx >> 4, k4 = idx & 15;
        WQ[0][k4 * 65 + c] = V4[(size_t)c * K4 + kc * 16 + k4];
      }
      __syncthreads();
      #pragma unroll 4
      for (int k4 = 0; k4 < 16; k4++){
        float4 w0 = WQ[0][k4 * 65 + lane];
        #pragma unroll
        for (int r = 0; r < RPW; r++){
          float4 xk = *(const float4*)&XS[r0 + r][kc * 64 + k4 * 4];
          acc0[r] += xk.x * w0.x + xk.y * w0.y + xk.z * w0.z + xk.w * w0.w;
        }
      }
    }
    if (lane < 2 * H){
      int h = lane >> 1;
      float* dst = (lane & 1) ? er : el;
      #pragma unroll
      for (int r = 0; r < RPW; r++){
        int row = rowbase + r0 + r;
        if (row < n) dst[(size_t)row * H + h] = acc0[r];
      }
    }
  }
}

// ---------------- GAT 1-head, float4 gather, NS edges/iter in lane-slots ----------------
// lane = slot q (edge) x float4-index j; final shfl_xor combine across slots.
template<int D>
__global__ void k_gat_h1(const int* __restrict__ rowptr, const int* __restrict__ esrc,
                         const float* __restrict__ z, const float* __restrict__ el,
                         const float* __restrict__ er, const float* __restrict__ b,
                         const float* __restrict__ zb, const float* __restrict__ bb,
                         float* __restrict__ out, int n){
  constexpr int LPS = D / 4;      // lanes per slot (32 for D=128, 16 for D=64)
  constexpr int NS  = 64 / LPS;   // edge slots per wave
  int lane = threadIdx.x & 63;
  int q = lane / LPS, j = lane % LPS;
  int i = blockIdx.x * (blockDim.x >> 6) + (threadIdx.x >> 6);
  if (i >= n) return;
  int s0 = rowptr[i], s1 = rowptr[i + 1];
  float eri = er[i];
  float m = -INFINITY;
  for (int e = s0 + lane; e < s1; e += 64)
    m = fmaxf(m, lrelu(el[esrc[e]] + eri));
  m = wred_max(m);
  float4 acc = make_float4(0.f, 0.f, 0.f, 0.f);
  float den = 0.f;
  for (int base = s0; base < s1; base += NS){
    int e = base + q;
    bool ok = (e < s1);
    int s = esrc[ok ? e : s0];
    float w = ok ? __expf(lrelu(el[s] + eri) - m) : 0.f;
    den += w;
    float4 zv = *(const float4*)&z[(size_t)s * D + 4 * j];
    acc.x += w * zv.x; acc.y += w * zv.y; acc.z += w * zv.z; acc.w += w * zv.w;
  }
  #pragma unroll
  for (int o = LPS; o < 64; o <<= 1){
    acc.x += __shfl_xor(acc.x, o);
    acc.y += __shfl_xor(acc.y, o);
    acc.z += __shfl_xor(acc.z, o);
    acc.w += __shfl_xor(acc.w, o);
    den   += __shfl_xor(den, o);
  }
  float inv = (s1 > s0) ? 1.f / den : 0.f;
  if (lane < LPS){
    float4 bv  = *(const float4*)&b[4 * j];
    float4 ch  = *(const float4*)&bb[4 * j];
    if (i > 0){
      float4 zbv = *(const float4*)&zb[(size_t)(i - 1) * D + 4 * j];
      ch.x += zbv.x; ch.y += zbv.y; ch.z += zbv.z; ch.w += zbv.w;
    }
    float4 o4;
    o4.x = 0.5f * ((acc.x * inv + bv.x) + ch.x);
    o4.y = 0.5f * ((acc.y * inv + bv.y) + ch.y);
    o4.z = 0.5f * ((acc.z * inv + bv.z) + ch.z);
    o4.w = 0.5f * ((acc.w * inv + bv.w) + ch.w);
    *(float4*)&out[(size_t)i * D + 4 * j] = o4;
  }
}

// ---------------- GAT 4-head, float4 gather: lane l -> head l>>4, cols 4l..4l+3 ----------------
__global__ void k_gat_mh(const int* __restrict__ rowptr, const int* __restrict__ esrc,
                         const float* __restrict__ z, const float* __restrict__ el,
                         const float* __restrict__ er, const float* __restrict__ b,
                         const float* __restrict__ zb, const float* __restrict__ bb,
                         float* __restrict__ out, int n){
  int lane = threadIdx.x & 63;
  int h = lane >> 4;
  int i = blockIdx.x * (blockDim.x >> 6) + (threadIdx.x >> 6);
  if (i >= n) return;
  int s0 = rowptr[i], s1 = rowptr[i + 1];
  const float4 eri4 = *(const float4*)(er + (size_t)i * 4);
  float m0 = -INFINITY, m1 = -INFINITY, m2 = -INFINITY, m3 = -INFINITY;
  for (int e = s0 + lane; e < s1; e += 64){
    float4 e4 = *(const float4*)(el + (size_t)esrc[e] * 4);
    m0 = fmaxf(m0, lrelu(e4.x + eri4.x));
    m1 = fmaxf(m1, lrelu(e4.y + eri4.y));
    m2 = fmaxf(m2, lrelu(e4.z + eri4.z));
    m3 = fmaxf(m3, lrelu(e4.w + eri4.w));
  }
  m0 = wred_max(m0); m1 = wred_max(m1); m2 = wred_max(m2); m3 = wred_max(m3);
  float msel = (h & 2) ? ((h & 1) ? m3 : m2) : ((h & 1) ? m1 : m0);
  float erh  = sel4(h, eri4);

  float4 acc  = make_float4(0.f, 0.f, 0.f, 0.f);
  float4 accB = make_float4(0.f, 0.f, 0.f, 0.f);
  float den = 0.f, denB = 0.f;
  int e = s0;
  for (; e + 1 < s1; e += 2){
    int sA = esrc[e], sB = esrc[e + 1];
    float4 eA = *(const float4*)(el + (size_t)sA * 4);
    float4 eB = *(const float4*)(el + (size_t)sB * 4);
    float wA = __expf(lrelu(sel4(h, eA) + erh) - msel);
    float wB = __expf(lrelu(sel4(h, eB) + erh) - msel);
    den += wA; denB += wB;
    float4 zA = *(const float4*)&z[(size_t)sA * 256 + 4 * lane];
    float4 zB = *(const float4*)&z[(size_t)sB * 256 + 4 * lane];
    acc.x  += wA * zA.x; acc.y  += wA * zA.y; acc.z  += wA * zA.z; acc.w  += wA * zA.w;
    accB.x += wB * zB.x; accB.y += wB * zB.y; accB.z += wB * zB.z; accB.w += wB * zB.w;
  }
  if (e < s1){
    int sA = esrc[e];
    float4 eA = *(const float4*)(el + (size_t)sA * 4);
    float wA = __expf(lrelu(sel4(h, eA) + erh) - msel);
    den += wA;
    float4 zA = *(const float4*)&z[(size_t)sA * 256 + 4 * lane];
    acc.x += wA * zA.x; acc.y += wA * zA.y; acc.z += wA * zA.z; acc.w += wA * zA.w;
  }
  den += denB;
  acc.x += accB.x; acc.y += accB.y; acc.z += accB.z; acc.w += accB.w;
  float inv = (s1 > s0) ? 1.f / den : 0.f;

  float4 bv = *(const float4*)&b[4 * lane];
  float4 ch = *(const float4*)&bb[4 * lane];
  if (i > 0){
    float4 zbv = *(const float4*)&zb[(size_t)(i - 1) * 256 + 4 * lane];
    ch.x += zbv.x; ch.y += zbv.y; ch.z += zbv.z; ch.w += zbv.w;
  }
  float4 o4;
  o4.x = 0.5f * ((acc.x * inv + bv.x) + ch.x);
  o4.y = 0.5f * ((acc.y * inv + bv.y) + ch.y);
  o4.z = 0.5f * ((acc.z * inv + bv.z) + ch.z);
  o4.w = 0.5f * ((acc.w * inv + bv.w) + ch.w);
  *(float4*)&out[(size_t)i * 256 + 4 * lane] = o4;
}

// ---------------- chain_pass ----------------
__global__ void k_chainpass64(const float* __restrict__ h, float* __restrict__ dh, int n){
  int lane = threadIdx.x & 63;
  int i = blockIdx.x * (blockDim.x >> 6) + (threadIdx.x >> 6);
  if (i >= n) return;
  float d = 0.f;
  if (i > 0) d = h[(size_t)(i - 1) * 64 + lane] - h[(size_t)i * 64 + lane];
  float ss = wred_sum(d * d);
  dh[(size_t)i * 64 + lane] = d / (sqrtf(ss) + 1e-7f);
}

__global__ void k_chainpass_mh(const float* __restrict__ hm, float* __restrict__ ds, int n){
  int lane = threadIdx.x & 63;
  int i = blockIdx.x * (blockDim.x >> 6) + (threadIdx.x >> 6);
  if (i >= n) return;
  const float* cur = hm + (size_t)i * 256;
  const float* prv = hm + (size_t)(i - 1) * 256;
  #pragma unroll
  for (int h = 0; h < 4; h++){
    int c = h * 64 + lane;
    float d = (i > 0) ? (prv[c] - cur[c]) : 0.f;
    float ss = wred_sum(d * d);
    ds[(size_t)i * 256 + c] = d / (sqrtf(ss) + 1e-7f);
  }
}

// ---------------- column-wise prefix sum over nodes (256 cols) ----------------
__global__ void k_chunk_sum(const float* __restrict__ ds, float* __restrict__ csum, int n, int ch){
  int b = blockIdx.x, t = threadIdx.x;
  int r0 = b * ch, r1 = r0 + ch; if (r1 > n) r1 = n;
  float s = 0.f;
  for (int r = r0; r < r1; r++) s += ds[(size_t)r * 256 + t];
  csum[(size_t)b * 256 + t] = s;
}
__global__ void k_scan_chunks_par(float* __restrict__ csum, int nb){
  __shared__ float s[512];
  int col = blockIdx.x;
  int t = threadIdx.x;
  s[t] = (t < nb) ? csum[(size_t)t * 256 + col] : 0.f;
  __syncthreads();
  #pragma unroll
  for (int o = 1; o < 512; o <<= 1){
    float add = (t >= o) ? s[t - o] : 0.f;
    __syncthreads();
    s[t] += add;
    __syncthreads();
  }
  if (t < nb) csum[(size_t)t * 256 + col] = (t > 0) ? s[t - 1] : 0.f;
}
__global__ void k_apply_scan(float* __restrict__ ds, const float* __restrict__ csum, int n, int ch){
  int b = blockIdx.x, t = threadIdx.x;
  int r0 = b * ch, r1 = r0 + ch; if (r1 > n) r1 = n;
  float run = csum[(size_t)b * 256 + t];
  for (int r = r0; r < r1; r++){
    run += ds[(size_t)r * 256 + t];
    ds[(size_t)r * 256 + t] = run;
  }
}

extern "C" void kernel_launch(void* const* d_in, const int* in_sizes, int n_in,
                              void* d_out, int out_size, void* d_ws, size_t ws_size,
                              hipStream_t stream){
  const float* x    = (const float*)d_in[0];
  const int*   src0 = (const int*)d_in[1];
  const int*   dst0 = (const int*)d_in[2];
  const float* W1a  = (const float*)d_in[5];
  const float* al1a = (const float*)d_in[6];
  const float* ar1a = (const float*)d_in[7];
  const float* b1a  = (const float*)d_in[8];
  const float* W1b  = (const float*)d_in[9];
  const float* b1b  = (const float*)d_in[12];
  const float* W2a  = (const float*)d_in[13];
  const float* al2a = (const float*)d_in[14];
  const float* ar2a = (const float*)d_in[15];
  const float* b2a  = (const float*)d_in[16];
  const float* W2b  = (const float*)d_in[17];
  const float* b2b  = (const float*)d_in[20];
  const float* Wma  = (const float*)d_in[21];
  const float* alma = (const float*)d_in[22];
  const float* arma = (const float*)d_in[23];
  const float* bma  = (const float*)d_in[24];
  const float* Wmb  = (const float*)d_in[25];
  const float* bmb  = (const float*)d_in[28];

  const int n = in_sizes[0] / 64;
  const int E = in_sizes[1];
  const size_t nf = (size_t)n;

  float* ws  = (float*)d_ws;
  float* A   = ws;
  float* B   = A + nf * 256;
  float* C   = B + nf * 256;
  float* D2  = C + nf * 256;   // h2 [n,64]
  float* E2  = D2 + nf * 64;   // dh [n,64]
  float* ela = E2 + nf * 64;   // [n,4]
  float* era = ela + nf * 4;
  const int ch = 100;
  const int nb = (n + ch - 1) / ch;      // 500 <= 512
  float* csum = era + nf * 4;  // [nb,256]
  int* deg    = (int*)(csum + (size_t)nb * 256);
  int* rowptr = deg + n;
  int* cursor = rowptr + (n + 1);
  int* esrc   = cursor + n;
  int* bsum   = esrc + E;
  float* vv1  = (float*)(bsum + 256);  // [2][64]
  float* vv2  = vv1 + 128;             // [2][128]
  float* vvm  = vv2 + 256;             // [8][64]

  float* dsout = (float*)d_out;

  const int nwb  = (n + 3) / 4;
  const int eb   = (E + 255) / 256;
  const int nblk = (n + 255) / 256;

  // CSR of interacts graph by dst (shared by all three GAT layers)
  hipMemsetAsync(deg, 0, (size_t)n * sizeof(int), stream);
  k_hist<<<eb, 256, 0, stream>>>(dst0, deg, E);
  k_deg_bsum<<<nblk, 256, 0, stream>>>(deg, bsum, n);
  k_bsum_scan<<<1, 256, 0, stream>>>(bsum, nblk);
  k_rowptr<<<nblk, 256, 0, stream>>>(deg, bsum, rowptr, cursor, n, E);
  k_scatter<<<eb, 256, 0, stream>>>(src0, dst0, cursor, esrc, E);

  // attention logit vectors
  k_valvar_all<<<3, 128, 0, stream>>>(W1a, al1a, ar1a, W2a, al2a, ar2a, Wma, alma, arma,
                                      vv1, vv2, vvm);

  // layer 1: in=64 -> hid=128 (a+b fused)
  k_gemm2<64, 128, 1><<<(n + 63) / 64, 256, 0, stream>>>(x, W1a, W1b, vv1, A, B, ela, era, n);
  k_gat_h1<128><<<nwb, 256, 0, stream>>>(rowptr, esrc, A, ela, era, b1a, B, b1b, C, n);

  // layer 2: hid=128 -> out=64 (a+b fused)
  k_gemm2<128, 64, 1><<<(n + 31) / 32, 256, 0, stream>>>(C, W2a, W2b, vv2, A, B, ela, era, n);
  k_gat_h1<64><<<nwb, 256, 0, stream>>>(rowptr, esrc, A, ela, era, b2a, B, b2b, D2, n);

  // dh = chain_pass(h2)
  k_chainpass64<<<nwb, 256, 0, stream>>>(D2, E2, n);

  // MH layer: out=64 -> 4 heads x 64 (a+b fused)
  k_gemm2<64, 256, 4><<<(n + 63) / 64, 256, 0, stream>>>(E2, Wma, Wmb, vvm, A, B, ela, era, n);
  k_gat_mh<<<nwb, 256, 0, stream>>>(rowptr, esrc, A, ela, era, bma, B, bmb, C, n);

  // ds = chain_pass(hm) -> staged directly in d_out
  k_chainpass_mh<<<nwb, 256, 0, stream>>>(C, dsout, n);

  // res = cumsum(ds, axis=0), in-place in d_out
  k_chunk_sum<<<nb, 256, 0, stream>>>(dsout, csum, n, ch);
  k_scan_chunks_par<<<256, 512, 0, stream>>>(csum, nb);
  k_apply_scan<<<nb, 256, 0, stream>>>(dsout, csum, n, ch);
}

// Round 9
// 691.145 us; speedup vs baseline: 6.8800x; 1.0015x over previous
//
#include <hip/hip_runtime.h>
#include <math.h>

__device__ __forceinline__ float wred_sum(float v){
  #pragma unroll
  for (int o = 32; o > 0; o >>= 1) v += __shfl_xor(v, o);
  return v;
}
__device__ __forceinline__ float wred_max(float v){
  #pragma unroll
  for (int o = 32; o > 0; o >>= 1) v = fmaxf(v, __shfl_xor(v, o));
  return v;
}
__device__ __forceinline__ float lrelu(float v){ return v > 0.f ? v : 0.2f * v; }
__device__ __forceinline__ float sel4(int h, float4 v){
  return (h & 2) ? ((h & 1) ? v.w : v.z) : ((h & 1) ? v.y : v.x);
}

// ---------------- CSR build (dst-sorted) ----------------
__global__ void k_hist(const int* __restrict__ dst, int* __restrict__ deg, int E){
  int t = blockIdx.x * blockDim.x + threadIdx.x;
  if (t < E) atomicAdd(&deg[dst[t]], 1);
}

__global__ void k_deg_bsum(const int* __restrict__ deg, int* __restrict__ bsum, int n){
  __shared__ int s[256];
  int b = blockIdx.x, t = threadIdx.x;
  int i = b * 256 + t;
  s[t] = (i < n) ? deg[i] : 0;
  __syncthreads();
  for (int o = 128; o > 0; o >>= 1){ if (t < o) s[t] += s[t + o]; __syncthreads(); }
  if (t == 0) bsum[b] = s[0];
}
__global__ void k_bsum_scan(int* __restrict__ bsum, int nblk){
  __shared__ int s[256];
  int t = threadIdx.x;
  s[t] = (t < nblk) ? bsum[t] : 0;
  __syncthreads();
  for (int o = 1; o < 256; o <<= 1){
    int add = (t >= o) ? s[t - o] : 0;
    __syncthreads();
    s[t] += add;
    __syncthreads();
  }
  if (t < nblk) bsum[t] = (t > 0) ? s[t - 1] : 0;
}
__global__ void k_rowptr(const int* __restrict__ deg, const int* __restrict__ bsum,
                         int* __restrict__ rowptr, int* __restrict__ cursor, int n, int E){
  __shared__ int s[256];
  int b = blockIdx.x, t = threadIdx.x;
  int i = b * 256 + t;
  int v = (i < n) ? deg[i] : 0;
  s[t] = v;
  __syncthreads();
  for (int o = 1; o < 256; o <<= 1){
    int add = (t >= o) ? s[t - o] : 0;
    __syncthreads();
    s[t] += add;
    __syncthreads();
  }
  if (i < n){
    int rp = bsum[b] + s[t] - v;
    rowptr[i] = rp;
    cursor[i] = rp;
    if (i == n - 1) rowptr[n] = E;
  }
}

__global__ void k_scatter(const int* __restrict__ src, const int* __restrict__ dst,
                          int* __restrict__ cursor, int* __restrict__ esrc, int E){
  int t = blockIdx.x * blockDim.x + threadIdx.x;
  if (t < E){
    int d = dst[t];
    int p = atomicAdd(&cursor[d], 1);
    esrc[p] = src[t];
  }
}

// ---------------- W transpose: W[C][K] -> WT4[k4][c] (float4 over k) ----------------
__global__ void k_wtrans_all(const float* __restrict__ W1a, const float* __restrict__ W1b,
                             const float* __restrict__ W2a, const float* __restrict__ W2b,
                             const float* __restrict__ Wma, const float* __restrict__ Wmb,
                             float4* __restrict__ T1a, float4* __restrict__ T1b,
                             float4* __restrict__ T2a, float4* __restrict__ T2b,
                             float4* __restrict__ Tma, float4* __restrict__ Tmb){
  int idx = blockIdx.x * 256 + threadIdx.x;
  const float* W; float4* T; int C, K4, off;
  if      (idx <  2048){ W = W1a; T = T1a; C = 128; K4 = 16; off = idx; }
  else if (idx <  4096){ W = W1b; T = T1b; C = 128; K4 = 16; off = idx - 2048; }
  else if (idx <  6144){ W = W2a; T = T2a; C =  64; K4 = 32; off = idx - 4096; }
  else if (idx <  8192){ W = W2b; T = T2b; C =  64; K4 = 32; off = idx - 6144; }
  else if (idx < 12288){ W = Wma; T = Tma; C = 256; K4 = 16; off = idx - 8192; }
  else if (idx < 16384){ W = Wmb; T = Tmb; C = 256; K4 = 16; off = idx - 12288; }
  else return;
  int c = off / K4, k4 = off - c * K4;
  const float* p = &W[(size_t)c * (K4 * 4) + 4 * k4];
  T[(size_t)k4 * C + c] = make_float4(p[0], p[1], p[2], p[3]);
}

// ---------------- attention-logit weights, transposed: vvT4[k4][c], c in [0,2H) ----------------
// c = 2h -> el weights (W^T al), c = 2h+1 -> er weights (W^T ar)
__global__ void k_valvar_all(const float* __restrict__ W1, const float* __restrict__ al1, const float* __restrict__ ar1,
                             const float* __restrict__ W2, const float* __restrict__ al2, const float* __restrict__ ar2,
                             const float* __restrict__ Wm, const float* __restrict__ alm, const float* __restrict__ arm,
                             float* __restrict__ vvT1, float* __restrict__ vvT2, float* __restrict__ vvTm){
  int b = blockIdx.x, k = threadIdx.x;
  if (b == 0){
    if (k < 64){ // L1: K=64, C=128, H=1
      float v = 0.f, w = 0.f;
      for (int c = 0; c < 128; c++){ float ww = W1[c * 64 + k]; v += al1[c] * ww; w += ar1[c] * ww; }
      vvT1[((k >> 2) * 2 + 0) * 4 + (k & 3)] = v;
      vvT1[((k >> 2) * 2 + 1) * 4 + (k & 3)] = w;
    }
  } else if (b == 1){ // L2: K=128, C=64, H=1
    float v = 0.f, w = 0.f;
    for (int c = 0; c < 64; c++){ float ww = W2[c * 128 + k]; v += al2[c] * ww; w += ar2[c] * ww; }
    vvT2[((k >> 2) * 2 + 0) * 4 + (k & 3)] = v;
    vvT2[((k >> 2) * 2 + 1) * 4 + (k & 3)] = w;
  } else {
    if (k < 64){ // MH: K=64, C=256, H=4
      for (int h = 0; h < 4; h++){
        float v = 0.f, w = 0.f;
        for (int c = 0; c < 64; c++){
          float ww = Wm[(size_t)(h * 64 + c) * 64 + k];
          v += alm[h * 64 + c] * ww; w += arm[h * 64 + c] * ww;
        }
        vvTm[((k >> 2) * 8 + 2 * h + 0) * 4 + (k & 3)] = v;
        vvTm[((k >> 2) * 8 + 2 * h + 1) * 4 + (k & 3)] = w;
      }
    }
  }
}

// ---------------- fused dual GEMM, W read coalesced from global (pre-transposed) ----------------
// LDS = XS only (16 KB) -> 8 blocks/CU; latency hidden by TLP (32 waves/CU).
// Lane owns column p*64+lane of both Wa and Wb; XS reads are wave-uniform broadcasts.
template<int K, int C, int H>
__global__ void k_gemm2t(const float* __restrict__ x,
                         const float4* __restrict__ WTa, const float4* __restrict__ WTb,
                         const float4* __restrict__ vvT,
                         float* __restrict__ za, float* __restrict__ zb,
                         float* __restrict__ el, float* __restrict__ er, int n){
  constexpr int K4 = K / 4, NCC = C / 64;
  constexpr int ROWS = 16384 / (K * 4);
  constexpr int RPW = ROWS / 4;
  __shared__ float XS[ROWS][K];

  int t = threadIdx.x, lane = t & 63, wv = t >> 6;
  int rowbase = blockIdx.x * ROWS;

  const float4* x4 = (const float4*)x;
  for (int idx = t; idx < ROWS * K4; idx += 256){
    int r = idx / K4, k4 = idx - r * K4;
    int row = rowbase + r;
    float4 v = make_float4(0.f, 0.f, 0.f, 0.f);
    if (row < n) v = x4[(size_t)row * K4 + k4];
    *(float4*)&XS[r][k4 * 4] = v;
  }
  __syncthreads();

  const int r0 = wv * RPW;
  float acc0[RPW], acc1[RPW];

  for (int p = 0; p < NCC; p++){
    #pragma unroll
    for (int r = 0; r < RPW; r++){ acc0[r] = 0.f; acc1[r] = 0.f; }
    const float4* Wa4 = WTa + (size_t)p * 64 + lane;
    const float4* Wb4 = WTb + (size_t)p * 64 + lane;
    #pragma unroll 2
    for (int k4 = 0; k4 < K4; k4++){
      float4 w0 = Wa4[(size_t)k4 * C];
      float4 w1 = Wb4[(size_t)k4 * C];
      #pragma unroll
      for (int r = 0; r < RPW; r++){
        float4 xk = *(const float4*)&XS[r0 + r][k4 * 4];
        acc0[r] += xk.x * w0.x + xk.y * w0.y + xk.z * w0.z + xk.w * w0.w;
        acc1[r] += xk.x * w1.x + xk.y * w1.y + xk.z * w1.z + xk.w * w1.w;
      }
    }
    #pragma unroll
    for (int r = 0; r < RPW; r++){
      int row = rowbase + r0 + r;
      if (row < n){
        za[(size_t)row * C + p * 64 + lane] = acc0[r];
        zb[(size_t)row * C + p * 64 + lane] = acc1[r];
      }
    }
  }

  // ext: el/er from vvT (cols 0..2H-1)
  if (lane < 2 * H){
    #pragma unroll
    for (int r = 0; r < RPW; r++) acc0[r] = 0.f;
    for (int k4 = 0; k4 < K4; k4++){
      float4 w0 = vvT[(size_t)k4 * (2 * H) + lane];
      #pragma unroll
      for (int r = 0; r < RPW; r++){
        float4 xk = *(const float4*)&XS[r0 + r][k4 * 4];
        acc0[r] += xk.x * w0.x + xk.y * w0.y + xk.z * w0.z + xk.w * w0.w;
      }
    }
    int h = lane >> 1;
    float* dst = (lane & 1) ? er : el;
    #pragma unroll
    for (int r = 0; r < RPW; r++){
      int row = rowbase + r0 + r;
      if (row < n) dst[(size_t)row * H + h] = acc0[r];
    }
  }
}

// ---------------- GAT 1-head, float4 gather, NS edges/iter in lane-slots ----------------
template<int D>
__global__ void k_gat_h1(const int* __restrict__ rowptr, const int* __restrict__ esrc,
                         const float* __restrict__ z, const float* __restrict__ el,
                         const float* __restrict__ er, const float* __restrict__ b,
                         const float* __restrict__ zb, const float* __restrict__ bb,
                         float* __restrict__ out, int n){
  constexpr int LPS = D / 4;
  constexpr int NS  = 64 / LPS;
  int lane = threadIdx.x & 63;
  int q = lane / LPS, j = lane % LPS;
  int i = blockIdx.x * (blockDim.x >> 6) + (threadIdx.x >> 6);
  if (i >= n) return;
  int s0 = rowptr[i], s1 = rowptr[i + 1];
  float eri = er[i];
  float m = -INFINITY;
  for (int e = s0 + lane; e < s1; e += 64)
    m = fmaxf(m, lrelu(el[esrc[e]] + eri));
  m = wred_max(m);
  float4 acc = make_float4(0.f, 0.f, 0.f, 0.f);
  float den = 0.f;
  for (int base = s0; base < s1; base += NS){
    int e = base + q;
    bool ok = (e < s1);
    int s = esrc[ok ? e : s0];
    float w = ok ? __expf(lrelu(el[s] + eri) - m) : 0.f;
    den += w;
    float4 zv = *(const float4*)&z[(size_t)s * D + 4 * j];
    acc.x += w * zv.x; acc.y += w * zv.y; acc.z += w * zv.z; acc.w += w * zv.w;
  }
  #pragma unroll
  for (int o = LPS; o < 64; o <<= 1){
    acc.x += __shfl_xor(acc.x, o);
    acc.y += __shfl_xor(acc.y, o);
    acc.z += __shfl_xor(acc.z, o);
    acc.w += __shfl_xor(acc.w, o);
    den   += __shfl_xor(den, o);
  }
  float inv = (s1 > s0) ? 1.f / den : 0.f;
  if (lane < LPS){
    float4 bv  = *(const float4*)&b[4 * j];
    float4 ch  = *(const float4*)&bb[4 * j];
    if (i > 0){
      float4 zbv = *(const float4*)&zb[(size_t)(i - 1) * D + 4 * j];
      ch.x += zbv.x; ch.y += zbv.y; ch.z += zbv.z; ch.w += zbv.w;
    }
    float4 o4;
    o4.x = 0.5f * ((acc.x * inv + bv.x) + ch.x);
    o4.y = 0.5f * ((acc.y * inv + bv.y) + ch.y);
    o4.z = 0.5f * ((acc.z * inv + bv.z) + ch.z);
    o4.w = 0.5f * ((acc.w * inv + bv.w) + ch.w);
    *(float4*)&out[(size_t)i * D + 4 * j] = o4;
  }
}

// ---------------- GAT 4-head, float4 gather ----------------
__global__ void k_gat_mh(const int* __restrict__ rowptr, const int* __restrict__ esrc,
                         const float* __restrict__ z, const float* __restrict__ el,
                         const float* __restrict__ er, const float* __restrict__ b,
                         const float* __restrict__ zb, const float* __restrict__ bb,
                         float* __restrict__ out, int n){
  int lane = threadIdx.x & 63;
  int h = lane >> 4;
  int i = blockIdx.x * (blockDim.x >> 6) + (threadIdx.x >> 6);
  if (i >= n) return;
  int s0 = rowptr[i], s1 = rowptr[i + 1];
  const float4 eri4 = *(const float4*)(er + (size_t)i * 4);
  float m0 = -INFINITY, m1 = -INFINITY, m2 = -INFINITY, m3 = -INFINITY;
  for (int e = s0 + lane; e < s1; e += 64){
    float4 e4 = *(const float4*)(el + (size_t)esrc[e] * 4);
    m0 = fmaxf(m0, lrelu(e4.x + eri4.x));
    m1 = fmaxf(m1, lrelu(e4.y + eri4.y));
    m2 = fmaxf(m2, lrelu(e4.z + eri4.z));
    m3 = fmaxf(m3, lrelu(e4.w + eri4.w));
  }
  m0 = wred_max(m0); m1 = wred_max(m1); m2 = wred_max(m2); m3 = wred_max(m3);
  float msel = (h & 2) ? ((h & 1) ? m3 : m2) : ((h & 1) ? m1 : m0);
  float erh  = sel4(h, eri4);

  float4 acc  = make_float4(0.f, 0.f, 0.f, 0.f);
  float4 accB = make_float4(0.f, 0.f, 0.f, 0.f);
  float den = 0.f, denB = 0.f;
  int e = s0;
  for (; e + 1 < s1; e += 2){
    int sA = esrc[e], sB = esrc[e + 1];
    float4 eA = *(const float4*)(el + (size_t)sA * 4);
    float4 eB = *(const float4*)(el + (size_t)sB * 4);
    float wA = __expf(lrelu(sel4(h, eA) + erh) - msel);
    float wB = __expf(lrelu(sel4(h, eB) + erh) - msel);
    den += wA; denB += wB;
    float4 zA = *(const float4*)&z[(size_t)sA * 256 + 4 * lane];
    float4 zB = *(const float4*)&z[(size_t)sB * 256 + 4 * lane];
    acc.x  += wA * zA.x; acc.y  += wA * zA.y; acc.z  += wA * zA.z; acc.w  += wA * zA.w;
    accB.x += wB * zB.x; accB.y += wB * zB.y; accB.z += wB * zB.z; accB.w += wB * zB.w;
  }
  if (e < s1){
    int sA = esrc[e];
    float4 eA = *(const float4*)(el + (size_t)sA * 4);
    float wA = __expf(lrelu(sel4(h, eA) + erh) - msel);
    den += wA;
    float4 zA = *(const float4*)&z[(size_t)sA * 256 + 4 * lane];
    acc.x += wA * zA.x; acc.y += wA * zA.y; acc.z += wA * zA.z; acc.w += wA * zA.w;
  }
  den += denB;
  acc.x += accB.x; acc.y += accB.y; acc.z += accB.z; acc.w += accB.w;
  float inv = (s1 > s0) ? 1.f / den : 0.f;

  float4 bv = *(const float4*)&b[4 * lane];
  float4 ch = *(const float4*)&bb[4 * lane];
  if (i > 0){
    float4 zbv = *(const float4*)&zb[(size_t)(i - 1) * 256 + 4 * lane];
    ch.x += zbv.x; ch.y += zbv.y; ch.z += zbv.z; ch.w += zbv.w;
  }
  float4 o4;
  o4.x = 0.5f * ((acc.x * inv + bv.x) + ch.x);
  o4.y = 0.5f * ((acc.y * inv + bv.y) + ch.y);
  o4.z = 0.5f * ((acc.z * inv + bv.z) + ch.z);
  o4.w = 0.5f * ((acc.w * inv + bv.w) + ch.w);
  *(float4*)&out[(size_t)i * 256 + 4 * lane] = o4;
}

// ---------------- chain_pass ----------------
__global__ void k_chainpass64(const float* __restrict__ h, float* __restrict__ dh, int n){
  int lane = threadIdx.x & 63;
  int i = blockIdx.x * (blockDim.x >> 6) + (threadIdx.x >> 6);
  if (i >= n) return;
  float d = 0.f;
  if (i > 0) d = h[(size_t)(i - 1) * 64 + lane] - h[(size_t)i * 64 + lane];
  float ss = wred_sum(d * d);
  dh[(size_t)i * 64 + lane] = d / (sqrtf(ss) + 1e-7f);
}

__global__ void k_chainpass_mh(const float* __restrict__ hm, float* __restrict__ ds, int n){
  int lane = threadIdx.x & 63;
  int i = blockIdx.x * (blockDim.x >> 6) + (threadIdx.x >> 6);
  if (i >= n) return;
  const float* cur = hm + (size_t)i * 256;
  const float* prv = hm + (size_t)(i - 1) * 256;
  #pragma unroll
  for (int h = 0; h < 4; h++){
    int c = h * 64 + lane;
    float d = (i > 0) ? (prv[c] - cur[c]) : 0.f;
    float ss = wred_sum(d * d);
    ds[(size_t)i * 256 + c] = d / (sqrtf(ss) + 1e-7f);
  }
}

// ---------------- column-wise prefix sum over nodes (256 cols) ----------------
__global__ void k_chunk_sum(const float* __restrict__ ds, float* __restrict__ csum, int n, int ch){
  int b = blockIdx.x, t = threadIdx.x;
  int r0 = b * ch, r1 = r0 + ch; if (r1 > n) r1 = n;
  float s = 0.f;
  for (int r = r0; r < r1; r++) s += ds[(size_t)r * 256 + t];
  csum[(size_t)b * 256 + t] = s;
}
__global__ void k_scan_chunks_par(float* __restrict__ csum, int nb){
  __shared__ float s[512];
  int col = blockIdx.x;
  int t = threadIdx.x;
  s[t] = (t < nb) ? csum[(size_t)t * 256 + col] : 0.f;
  __syncthreads();
  #pragma unroll
  for (int o = 1; o < 512; o <<= 1){
    float add = (t >= o) ? s[t - o] : 0.f;
    __syncthreads();
    s[t] += add;
    __syncthreads();
  }
  if (t < nb) csum[(size_t)t * 256 + col] = (t > 0) ? s[t - 1] : 0.f;
}
__global__ void k_apply_scan(float* __restrict__ ds, const float* __restrict__ csum, int n, int ch){
  int b = blockIdx.x, t = threadIdx.x;
  int r0 = b * ch, r1 = r0 + ch; if (r1 > n) r1 = n;
  float run = csum[(size_t)b * 256 + t];
  for (int r = r0; r < r1; r++){
    run += ds[(size_t)r * 256 + t];
    ds[(size_t)r * 256 + t] = run;
  }
}

extern "C" void kernel_launch(void* const* d_in, const int* in_sizes, int n_in,
                              void* d_out, int out_size, void* d_ws, size_t ws_size,
                              hipStream_t stream){
  const float* x    = (const float*)d_in[0];
  const int*   src0 = (const int*)d_in[1];
  const int*   dst0 = (const int*)d_in[2];
  const float* W1a  = (const float*)d_in[5];
  const float* al1a = (const float*)d_in[6];
  const float* ar1a = (const float*)d_in[7];
  const float* b1a  = (const float*)d_in[8];
  const float* W1b  = (const float*)d_in[9];
  const float* b1b  = (const float*)d_in[12];
  const float* W2a  = (const float*)d_in[13];
  const float* al2a = (const float*)d_in[14];
  const float* ar2a = (const float*)d_in[15];
  const float* b2a  = (const float*)d_in[16];
  const float* W2b  = (const float*)d_in[17];
  const float* b2b  = (const float*)d_in[20];
  const float* Wma  = (const float*)d_in[21];
  const float* alma = (const float*)d_in[22];
  const float* arma = (const float*)d_in[23];
  const float* bma  = (const float*)d_in[24];
  const float* Wmb  = (const float*)d_in[25];
  const float* bmb  = (const float*)d_in[28];

  const int n = in_sizes[0] / 64;
  const int E = in_sizes[1];
  const size_t nf = (size_t)n;

  float* ws  = (float*)d_ws;
  float* A   = ws;
  float* B   = A + nf * 256;
  float* C   = B + nf * 256;
  float* D2  = C + nf * 256;   // h2 [n,64]
  float* E2  = D2 + nf * 64;   // dh [n,64]
  float* ela = E2 + nf * 64;   // [n,4]
  float* era = ela + nf * 4;
  const int ch = 100;
  const int nb = (n + ch - 1) / ch;      // 500 <= 512
  float* csum = era + nf * 4;  // [nb,256]
  // 16B-aligned region for transposed weights (all offsets below stay 16B-aligned)
  float* wtbase = csum + (size_t)nb * 256;
  float4* T1a = (float4*)wtbase;          // [16][128] f4 = 2048
  float4* T1b = T1a + 2048;
  float4* T2a = T1b + 2048;               // [32][64]  f4 = 2048
  float4* T2b = T2a + 2048;
  float4* Tma = T2b + 2048;               // [16][256] f4 = 4096
  float4* Tmb = Tma + 4096;
  float* vvT1 = (float*)(Tmb + 4096);     // [16][2] f4 -> 128 floats
  float* vvT2 = vvT1 + 128;               // [32][2] f4 -> 256 floats
  float* vvTm = vvT2 + 256;               // [16][8] f4 -> 512 floats
  int* deg    = (int*)(vvTm + 512);
  int* rowptr = deg + n;
  int* cursor = rowptr + (n + 16);
  int* esrc   = cursor + n;
  int* bsum   = esrc + E;

  float* dsout = (float*)d_out;

  const int nwb  = (n + 3) / 4;
  const int eb   = (E + 255) / 256;
  const int nblk = (n + 255) / 256;

  // CSR of interacts graph by dst (shared by all three GAT layers)
  hipMemsetAsync(deg, 0, (size_t)n * sizeof(int), stream);
  k_hist<<<eb, 256, 0, stream>>>(dst0, deg, E);
  k_deg_bsum<<<nblk, 256, 0, stream>>>(deg, bsum, n);
  k_bsum_scan<<<1, 256, 0, stream>>>(bsum, nblk);
  k_rowptr<<<nblk, 256, 0, stream>>>(deg, bsum, rowptr, cursor, n, E);
  k_scatter<<<eb, 256, 0, stream>>>(src0, dst0, cursor, esrc, E);

  // weight preprocessing
  k_wtrans_all<<<64, 256, 0, stream>>>(W1a, W1b, W2a, W2b, Wma, Wmb,
                                       T1a, T1b, T2a, T2b, Tma, Tmb);
  k_valvar_all<<<3, 128, 0, stream>>>(W1a, al1a, ar1a, W2a, al2a, ar2a, Wma, alma, arma,
                                      vvT1, vvT2, vvTm);

  // layer 1: in=64 -> hid=128 (a+b fused)
  k_gemm2t<64, 128, 1><<<(n + 63) / 64, 256, 0, stream>>>(x, T1a, T1b, (const float4*)vvT1, A, B, ela, era, n);
  k_gat_h1<128><<<nwb, 256, 0, stream>>>(rowptr, esrc, A, ela, era, b1a, B, b1b, C, n);

  // layer 2: hid=128 -> out=64 (a+b fused)
  k_gemm2t<128, 64, 1><<<(n + 31) / 32, 256, 0, stream>>>(C, T2a, T2b, (const float4*)vvT2, A, B, ela, era, n);
  k_gat_h1<64><<<nwb, 256, 0, stream>>>(rowptr, esrc, A, ela, era, b2a, B, b2b, D2, n);

  // dh = chain_pass(h2)
  k_chainpass64<<<nwb, 256, 0, stream>>>(D2, E2, n);

  // MH layer: out=64 -> 4 heads x 64 (a+b fused)
  k_gemm2t<64, 256, 4><<<(n + 63) / 64, 256, 0, stream>>>(E2, Tma, Tmb, (const float4*)vvTm, A, B, ela, era, n);
  k_gat_mh<<<nwb, 256, 0, stream>>>(rowptr, esrc, A, ela, era, bma, B, bmb, C, n);

  // ds = chain_pass(hm) -> staged directly in d_out
  k_chainpass_mh<<<nwb, 256, 0, stream>>>(C, dsout, n);

  // res = cumsum(ds, axis=0), in-place in d_out
  k_chunk_sum<<<nb, 256, 0, stream>>>(dsout, csum, n, ch);
  k_scan_chunks_par<<<256, 512, 0, stream>>>(csum, nb);
  k_apply_scan<<<nb, 256, 0, stream>>>(dsout, csum, n, ch);
}

// Round 10
// 636.830 us; speedup vs baseline: 7.4668x; 1.0853x over previous
//
#include <hip/hip_runtime.h>
#include <math.h>

__device__ __forceinline__ float wred_sum(float v){
  #pragma unroll
  for (int o = 32; o > 0; o >>= 1) v += __shfl_xor(v, o);
  return v;
}
__device__ __forceinline__ float wred_max(float v){
  #pragma unroll
  for (int o = 32; o > 0; o >>= 1) v = fmaxf(v, __shfl_xor(v, o));
  return v;
}
__device__ __forceinline__ float lrelu(float v){ return v > 0.f ? v : 0.2f * v; }
__device__ __forceinline__ float sel4(int h, float4 v){
  return (h & 2) ? ((h & 1) ? v.w : v.z) : ((h & 1) ? v.y : v.x);
}

// ---------------- CSR build (dst-sorted) ----------------
__global__ void k_hist(const int* __restrict__ dst, int* __restrict__ deg, int E){
  int t = blockIdx.x * blockDim.x + threadIdx.x;
  if (t < E) atomicAdd(&deg[dst[t]], 1);
}

__global__ void k_deg_bsum(const int* __restrict__ deg, int* __restrict__ bsum, int n){
  __shared__ int s[256];
  int b = blockIdx.x, t = threadIdx.x;
  int i = b * 256 + t;
  s[t] = (i < n) ? deg[i] : 0;
  __syncthreads();
  for (int o = 128; o > 0; o >>= 1){ if (t < o) s[t] += s[t + o]; __syncthreads(); }
  if (t == 0) bsum[b] = s[0];
}
__global__ void k_bsum_scan(int* __restrict__ bsum, int nblk){
  __shared__ int s[256];
  int t = threadIdx.x;
  s[t] = (t < nblk) ? bsum[t] : 0;
  __syncthreads();
  for (int o = 1; o < 256; o <<= 1){
    int add = (t >= o) ? s[t - o] : 0;
    __syncthreads();
    s[t] += add;
    __syncthreads();
  }
  if (t < nblk) bsum[t] = (t > 0) ? s[t - 1] : 0;
}
__global__ void k_rowptr(const int* __restrict__ deg, const int* __restrict__ bsum,
                         int* __restrict__ rowptr, int* __restrict__ cursor, int n, int E){
  __shared__ int s[256];
  int b = blockIdx.x, t = threadIdx.x;
  int i = b * 256 + t;
  int v = (i < n) ? deg[i] : 0;
  s[t] = v;
  __syncthreads();
  for (int o = 1; o < 256; o <<= 1){
    int add = (t >= o) ? s[t - o] : 0;
    __syncthreads();
    s[t] += add;
    __syncthreads();
  }
  if (i < n){
    int rp = bsum[b] + s[t] - v;
    rowptr[i] = rp;
    cursor[i] = rp;
    if (i == n - 1) rowptr[n] = E;
  }
}

__global__ void k_scatter(const int* __restrict__ src, const int* __restrict__ dst,
                          int* __restrict__ cursor, int* __restrict__ esrc, int E){
  int t = blockIdx.x * blockDim.x + threadIdx.x;
  if (t < E){
    int d = dst[t];
    int p = atomicAdd(&cursor[d], 1);
    esrc[p] = src[t];
  }
}

// ---------------- W transpose: W[C][K] -> WT4[k4][c] (float4 over k) ----------------
__global__ void k_wtrans_all(const float* __restrict__ W1a, const float* __restrict__ W1b,
                             const float* __restrict__ W2a, const float* __restrict__ W2b,
                             const float* __restrict__ Wma, const float* __restrict__ Wmb,
                             float4* __restrict__ T1a, float4* __restrict__ T1b,
                             float4* __restrict__ T2a, float4* __restrict__ T2b,
                             float4* __restrict__ Tma, float4* __restrict__ Tmb){
  int idx = blockIdx.x * 256 + threadIdx.x;
  const float* W; float4* T; int C, K4, off;
  if      (idx <  2048){ W = W1a; T = T1a; C = 128; K4 = 16; off = idx; }
  else if (idx <  4096){ W = W1b; T = T1b; C = 128; K4 = 16; off = idx - 2048; }
  else if (idx <  6144){ W = W2a; T = T2a; C =  64; K4 = 32; off = idx - 4096; }
  else if (idx <  8192){ W = W2b; T = T2b; C =  64; K4 = 32; off = idx - 6144; }
  else if (idx < 12288){ W = Wma; T = Tma; C = 256; K4 = 16; off = idx - 8192; }
  else if (idx < 16384){ W = Wmb; T = Tmb; C = 256; K4 = 16; off = idx - 12288; }
  else return;
  int c = off / K4, k4 = off - c * K4;
  const float* p = &W[(size_t)c * (K4 * 4) + 4 * k4];
  T[(size_t)k4 * C + c] = make_float4(p[0], p[1], p[2], p[3]);
}

// ---------------- attention-logit weights, transposed: vvT4[k4][c], c in [0,2H) ----------------
__global__ void k_valvar_all(const float* __restrict__ W1, const float* __restrict__ al1, const float* __restrict__ ar1,
                             const float* __restrict__ W2, const float* __restrict__ al2, const float* __restrict__ ar2,
                             const float* __restrict__ Wm, const float* __restrict__ alm, const float* __restrict__ arm,
                             float* __restrict__ vvT1, float* __restrict__ vvT2, float* __restrict__ vvTm){
  int b = blockIdx.x, k = threadIdx.x;
  if (b == 0){
    if (k < 64){ // L1: K=64, C=128, H=1
      float v = 0.f, w = 0.f;
      for (int c = 0; c < 128; c++){ float ww = W1[c * 64 + k]; v += al1[c] * ww; w += ar1[c] * ww; }
      vvT1[((k >> 2) * 2 + 0) * 4 + (k & 3)] = v;
      vvT1[((k >> 2) * 2 + 1) * 4 + (k & 3)] = w;
    }
  } else if (b == 1){ // L2: K=128, C=64, H=1
    float v = 0.f, w = 0.f;
    for (int c = 0; c < 64; c++){ float ww = W2[c * 128 + k]; v += al2[c] * ww; w += ar2[c] * ww; }
    vvT2[((k >> 2) * 2 + 0) * 4 + (k & 3)] = v;
    vvT2[((k >> 2) * 2 + 1) * 4 + (k & 3)] = w;
  } else {
    if (k < 64){ // MH: K=64, C=256, H=4
      for (int h = 0; h < 4; h++){
        float v = 0.f, w = 0.f;
        for (int c = 0; c < 64; c++){
          float ww = Wm[(size_t)(h * 64 + c) * 64 + k];
          v += alm[h * 64 + c] * ww; w += arm[h * 64 + c] * ww;
        }
        vvTm[((k >> 2) * 8 + 2 * h + 0) * 4 + (k & 3)] = v;
        vvTm[((k >> 2) * 8 + 2 * h + 1) * 4 + (k & 3)] = w;
      }
    }
  }
}

// ---------------- fused dual GEMM, chunk-parallel over grid.y ----------------
// blockIdx.y = p: p < NCC -> 64-col chunk p of both Wa and Wb; p == NCC -> logit ext.
// LDS = XS only (16 KB); ~15 blocks/CU supply TLP to hide ds_read/global latency.
template<int K, int C, int H>
__global__ void k_gemm2t(const float* __restrict__ x,
                         const float4* __restrict__ WTa, const float4* __restrict__ WTb,
                         const float4* __restrict__ vvT,
                         float* __restrict__ za, float* __restrict__ zb,
                         float* __restrict__ el, float* __restrict__ er, int n){
  constexpr int K4 = K / 4, NCC = C / 64;
  constexpr int ROWS = 16384 / (K * 4);
  constexpr int RPW = ROWS / 4;
  __shared__ float XS[ROWS][K];

  int t = threadIdx.x, lane = t & 63, wv = t >> 6;
  int rowbase = blockIdx.x * ROWS;
  int p = blockIdx.y;

  const float4* x4 = (const float4*)x;
  for (int idx = t; idx < ROWS * K4; idx += 256){
    int r = idx / K4, k4 = idx - r * K4;
    int row = rowbase + r;
    float4 v = make_float4(0.f, 0.f, 0.f, 0.f);
    if (row < n) v = x4[(size_t)row * K4 + k4];
    *(float4*)&XS[r][k4 * 4] = v;
  }
  __syncthreads();

  const int r0 = wv * RPW;
  float acc0[RPW], acc1[RPW];

  if (p < NCC){
    #pragma unroll
    for (int r = 0; r < RPW; r++){ acc0[r] = 0.f; acc1[r] = 0.f; }
    const float4* Wa4 = WTa + (size_t)p * 64 + lane;
    const float4* Wb4 = WTb + (size_t)p * 64 + lane;
    #pragma unroll 2
    for (int k4 = 0; k4 < K4; k4++){
      float4 w0 = Wa4[(size_t)k4 * C];
      float4 w1 = Wb4[(size_t)k4 * C];
      #pragma unroll
      for (int r = 0; r < RPW; r++){
        float4 xk = *(const float4*)&XS[r0 + r][k4 * 4];
        acc0[r] += xk.x * w0.x + xk.y * w0.y + xk.z * w0.z + xk.w * w0.w;
        acc1[r] += xk.x * w1.x + xk.y * w1.y + xk.z * w1.z + xk.w * w1.w;
      }
    }
    #pragma unroll
    for (int r = 0; r < RPW; r++){
      int row = rowbase + r0 + r;
      if (row < n){
        za[(size_t)row * C + p * 64 + lane] = acc0[r];
        zb[(size_t)row * C + p * 64 + lane] = acc1[r];
      }
    }
  } else if (lane < 2 * H){
    // ext: el/er from vvT (cols 0..2H-1)
    #pragma unroll
    for (int r = 0; r < RPW; r++) acc0[r] = 0.f;
    for (int k4 = 0; k4 < K4; k4++){
      float4 w0 = vvT[(size_t)k4 * (2 * H) + lane];
      #pragma unroll
      for (int r = 0; r < RPW; r++){
        float4 xk = *(const float4*)&XS[r0 + r][k4 * 4];
        acc0[r] += xk.x * w0.x + xk.y * w0.y + xk.z * w0.z + xk.w * w0.w;
      }
    }
    int h = lane >> 1;
    float* dst = (lane & 1) ? er : el;
    #pragma unroll
    for (int r = 0; r < RPW; r++){
      int row = rowbase + r0 + r;
      if (row < n) dst[(size_t)row * H + h] = acc0[r];
    }
  }
}

// ---------------- GAT 1-head, float4 gather, NS edges/iter in lane-slots ----------------
template<int D>
__global__ void k_gat_h1(const int* __restrict__ rowptr, const int* __restrict__ esrc,
                         const float* __restrict__ z, const float* __restrict__ el,
                         const float* __restrict__ er, const float* __restrict__ b,
                         const float* __restrict__ zb, const float* __restrict__ bb,
                         float* __restrict__ out, int n){
  constexpr int LPS = D / 4;
  constexpr int NS  = 64 / LPS;
  int lane = threadIdx.x & 63;
  int q = lane / LPS, j = lane % LPS;
  int i = blockIdx.x * (blockDim.x >> 6) + (threadIdx.x >> 6);
  if (i >= n) return;
  int s0 = rowptr[i], s1 = rowptr[i + 1];
  float eri = er[i];
  float m = -INFINITY;
  for (int e = s0 + lane; e < s1; e += 64)
    m = fmaxf(m, lrelu(el[esrc[e]] + eri));
  m = wred_max(m);
  float4 acc = make_float4(0.f, 0.f, 0.f, 0.f);
  float den = 0.f;
  for (int base = s0; base < s1; base += NS){
    int e = base + q;
    bool ok = (e < s1);
    int s = esrc[ok ? e : s0];
    float w = ok ? __expf(lrelu(el[s] + eri) - m) : 0.f;
    den += w;
    float4 zv = *(const float4*)&z[(size_t)s * D + 4 * j];
    acc.x += w * zv.x; acc.y += w * zv.y; acc.z += w * zv.z; acc.w += w * zv.w;
  }
  #pragma unroll
  for (int o = LPS; o < 64; o <<= 1){
    acc.x += __shfl_xor(acc.x, o);
    acc.y += __shfl_xor(acc.y, o);
    acc.z += __shfl_xor(acc.z, o);
    acc.w += __shfl_xor(acc.w, o);
    den   += __shfl_xor(den, o);
  }
  float inv = (s1 > s0) ? 1.f / den : 0.f;
  if (lane < LPS){
    float4 bv  = *(const float4*)&b[4 * j];
    float4 ch  = *(const float4*)&bb[4 * j];
    if (i > 0){
      float4 zbv = *(const float4*)&zb[(size_t)(i - 1) * D + 4 * j];
      ch.x += zbv.x; ch.y += zbv.y; ch.z += zbv.z; ch.w += zbv.w;
    }
    float4 o4;
    o4.x = 0.5f * ((acc.x * inv + bv.x) + ch.x);
    o4.y = 0.5f * ((acc.y * inv + bv.y) + ch.y);
    o4.z = 0.5f * ((acc.z * inv + bv.z) + ch.z);
    o4.w = 0.5f * ((acc.w * inv + bv.w) + ch.w);
    *(float4*)&out[(size_t)i * D + 4 * j] = o4;
  }
}

// ---------------- GAT 4-head, float4 gather ----------------
__global__ void k_gat_mh(const int* __restrict__ rowptr, const int* __restrict__ esrc,
                         const float* __restrict__ z, const float* __restrict__ el,
                         const float* __restrict__ er, const float* __restrict__ b,
                         const float* __restrict__ zb, const float* __restrict__ bb,
                         float* __restrict__ out, int n){
  int lane = threadIdx.x & 63;
  int h = lane >> 4;
  int i = blockIdx.x * (blockDim.x >> 6) + (threadIdx.x >> 6);
  if (i >= n) return;
  int s0 = rowptr[i], s1 = rowptr[i + 1];
  const float4 eri4 = *(const float4*)(er + (size_t)i * 4);
  float m0 = -INFINITY, m1 = -INFINITY, m2 = -INFINITY, m3 = -INFINITY;
  for (int e = s0 + lane; e < s1; e += 64){
    float4 e4 = *(const float4*)(el + (size_t)esrc[e] * 4);
    m0 = fmaxf(m0, lrelu(e4.x + eri4.x));
    m1 = fmaxf(m1, lrelu(e4.y + eri4.y));
    m2 = fmaxf(m2, lrelu(e4.z + eri4.z));
    m3 = fmaxf(m3, lrelu(e4.w + eri4.w));
  }
  m0 = wred_max(m0); m1 = wred_max(m1); m2 = wred_max(m2); m3 = wred_max(m3);
  float msel = (h & 2) ? ((h & 1) ? m3 : m2) : ((h & 1) ? m1 : m0);
  float erh  = sel4(h, eri4);

  float4 acc  = make_float4(0.f, 0.f, 0.f, 0.f);
  float4 accB = make_float4(0.f, 0.f, 0.f, 0.f);
  float den = 0.f, denB = 0.f;
  int e = s0;
  for (; e + 1 < s1; e += 2){
    int sA = esrc[e], sB = esrc[e + 1];
    float4 eA = *(const float4*)(el + (size_t)sA * 4);
    float4 eB = *(const float4*)(el + (size_t)sB * 4);
    float wA = __expf(lrelu(sel4(h, eA) + erh) - msel);
    float wB = __expf(lrelu(sel4(h, eB) + erh) - msel);
    den += wA; denB += wB;
    float4 zA = *(const float4*)&z[(size_t)sA * 256 + 4 * lane];
    float4 zB = *(const float4*)&z[(size_t)sB * 256 + 4 * lane];
    acc.x  += wA * zA.x; acc.y  += wA * zA.y; acc.z  += wA * zA.z; acc.w  += wA * zA.w;
    accB.x += wB * zB.x; accB.y += wB * zB.y; accB.z += wB * zB.z; accB.w += wB * zB.w;
  }
  if (e < s1){
    int sA = esrc[e];
    float4 eA = *(const float4*)(el + (size_t)sA * 4);
    float wA = __expf(lrelu(sel4(h, eA) + erh) - msel);
    den += wA;
    float4 zA = *(const float4*)&z[(size_t)sA * 256 + 4 * lane];
    acc.x += wA * zA.x; acc.y += wA * zA.y; acc.z += wA * zA.z; acc.w += wA * zA.w;
  }
  den += denB;
  acc.x += accB.x; acc.y += accB.y; acc.z += accB.z; acc.w += accB.w;
  float inv = (s1 > s0) ? 1.f / den : 0.f;

  float4 bv = *(const float4*)&b[4 * lane];
  float4 ch = *(const float4*)&bb[4 * lane];
  if (i > 0){
    float4 zbv = *(const float4*)&zb[(size_t)(i - 1) * 256 + 4 * lane];
    ch.x += zbv.x; ch.y += zbv.y; ch.z += zbv.z; ch.w += zbv.w;
  }
  float4 o4;
  o4.x = 0.5f * ((acc.x * inv + bv.x) + ch.x);
  o4.y = 0.5f * ((acc.y * inv + bv.y) + ch.y);
  o4.z = 0.5f * ((acc.z * inv + bv.z) + ch.z);
  o4.w = 0.5f * ((acc.w * inv + bv.w) + ch.w);
  *(float4*)&out[(size_t)i * 256 + 4 * lane] = o4;
}

// ---------------- chain_pass ----------------
__global__ void k_chainpass64(const float* __restrict__ h, float* __restrict__ dh, int n){
  int lane = threadIdx.x & 63;
  int i = blockIdx.x * (blockDim.x >> 6) + (threadIdx.x >> 6);
  if (i >= n) return;
  float d = 0.f;
  if (i > 0) d = h[(size_t)(i - 1) * 64 + lane] - h[(size_t)i * 64 + lane];
  float ss = wred_sum(d * d);
  dh[(size_t)i * 64 + lane] = d / (sqrtf(ss) + 1e-7f);
}

__global__ void k_chainpass_mh(const float* __restrict__ hm, float* __restrict__ ds, int n){
  int lane = threadIdx.x & 63;
  int i = blockIdx.x * (blockDim.x >> 6) + (threadIdx.x >> 6);
  if (i >= n) return;
  const float* cur = hm + (size_t)i * 256;
  const float* prv = hm + (size_t)(i - 1) * 256;
  #pragma unroll
  for (int h = 0; h < 4; h++){
    int c = h * 64 + lane;
    float d = (i > 0) ? (prv[c] - cur[c]) : 0.f;
    float ss = wred_sum(d * d);
    ds[(size_t)i * 256 + c] = d / (sqrtf(ss) + 1e-7f);
  }
}

// ---------------- column-wise prefix sum over nodes (256 cols) ----------------
__global__ void k_chunk_sum(const float* __restrict__ ds, float* __restrict__ csum, int n, int ch){
  int b = blockIdx.x, t = threadIdx.x;
  int r0 = b * ch, r1 = r0 + ch; if (r1 > n) r1 = n;
  float s = 0.f;
  for (int r = r0; r < r1; r++) s += ds[(size_t)r * 256 + t];
  csum[(size_t)b * 256 + t] = s;
}
__global__ void k_scan_chunks_par(float* __restrict__ csum, int nb){
  __shared__ float s[512];
  int col = blockIdx.x;
  int t = threadIdx.x;
  s[t] = (t < nb) ? csum[(size_t)t * 256 + col] : 0.f;
  __syncthreads();
  #pragma unroll
  for (int o = 1; o < 512; o <<= 1){
    float add = (t >= o) ? s[t - o] : 0.f;
    __syncthreads();
    s[t] += add;
    __syncthreads();
  }
  if (t < nb) csum[(size_t)t * 256 + col] = (t > 0) ? s[t - 1] : 0.f;
}
__global__ void k_apply_scan(float* __restrict__ ds, const float* __restrict__ csum, int n, int ch){
  int b = blockIdx.x, t = threadIdx.x;
  int r0 = b * ch, r1 = r0 + ch; if (r1 > n) r1 = n;
  float run = csum[(size_t)b * 256 + t];
  for (int r = r0; r < r1; r++){
    run += ds[(size_t)r * 256 + t];
    ds[(size_t)r * 256 + t] = run;
  }
}

extern "C" void kernel_launch(void* const* d_in, const int* in_sizes, int n_in,
                              void* d_out, int out_size, void* d_ws, size_t ws_size,
                              hipStream_t stream){
  const float* x    = (const float*)d_in[0];
  const int*   src0 = (const int*)d_in[1];
  const int*   dst0 = (const int*)d_in[2];
  const float* W1a  = (const float*)d_in[5];
  const float* al1a = (const float*)d_in[6];
  const float* ar1a = (const float*)d_in[7];
  const float* b1a  = (const float*)d_in[8];
  const float* W1b  = (const float*)d_in[9];
  const float* b1b  = (const float*)d_in[12];
  const float* W2a  = (const float*)d_in[13];
  const float* al2a = (const float*)d_in[14];
  const float* ar2a = (const float*)d_in[15];
  const float* b2a  = (const float*)d_in[16];
  const float* W2b  = (const float*)d_in[17];
  const float* b2b  = (const float*)d_in[20];
  const float* Wma  = (const float*)d_in[21];
  const float* alma = (const float*)d_in[22];
  const float* arma = (const float*)d_in[23];
  const float* bma  = (const float*)d_in[24];
  const float* Wmb  = (const float*)d_in[25];
  const float* bmb  = (const float*)d_in[28];

  const int n = in_sizes[0] / 64;
  const int E = in_sizes[1];
  const size_t nf = (size_t)n;

  float* ws  = (float*)d_ws;
  float* A   = ws;
  float* B   = A + nf * 256;
  float* C   = B + nf * 256;
  float* D2  = C + nf * 256;   // h2 [n,64]
  float* E2  = D2 + nf * 64;   // dh [n,64]
  float* ela = E2 + nf * 64;   // [n,4]
  float* era = ela + nf * 4;
  const int ch = 100;
  const int nb = (n + ch - 1) / ch;      // 500 <= 512
  float* csum = era + nf * 4;  // [nb,256]
  float* wtbase = csum + (size_t)nb * 256;
  float4* T1a = (float4*)wtbase;          // [16][128] f4 = 2048
  float4* T1b = T1a + 2048;
  float4* T2a = T1b + 2048;               // [32][64]  f4 = 2048
  float4* T2b = T2a + 2048;
  float4* Tma = T2b + 2048;               // [16][256] f4 = 4096
  float4* Tmb = Tma + 4096;
  float* vvT1 = (float*)(Tmb + 4096);     // [16][2] f4 -> 128 floats
  float* vvT2 = vvT1 + 128;               // [32][2] f4 -> 256 floats
  float* vvTm = vvT2 + 256;               // [16][8] f4 -> 512 floats
  int* deg    = (int*)(vvTm + 512);
  int* rowptr = deg + n;
  int* cursor = rowptr + (n + 16);
  int* esrc   = cursor + n;
  int* bsum   = esrc + E;

  float* dsout = (float*)d_out;

  const int nwb  = (n + 3) / 4;
  const int eb   = (E + 255) / 256;
  const int nblk = (n + 255) / 256;

  // CSR of interacts graph by dst (shared by all three GAT layers)
  hipMemsetAsync(deg, 0, (size_t)n * sizeof(int), stream);
  k_hist<<<eb, 256, 0, stream>>>(dst0, deg, E);
  k_deg_bsum<<<nblk, 256, 0, stream>>>(deg, bsum, n);
  k_bsum_scan<<<1, 256, 0, stream>>>(bsum, nblk);
  k_rowptr<<<nblk, 256, 0, stream>>>(deg, bsum, rowptr, cursor, n, E);
  k_scatter<<<eb, 256, 0, stream>>>(src0, dst0, cursor, esrc, E);

  // weight preprocessing
  k_wtrans_all<<<64, 256, 0, stream>>>(W1a, W1b, W2a, W2b, Wma, Wmb,
                                       T1a, T1b, T2a, T2b, Tma, Tmb);
  k_valvar_all<<<3, 128, 0, stream>>>(W1a, al1a, ar1a, W2a, al2a, ar2a, Wma, alma, arma,
                                      vvT1, vvT2, vvTm);

  // layer 1: in=64 -> hid=128 (a+b fused; chunk-parallel grid.y = {0,1,ext})
  k_gemm2t<64, 128, 1><<<dim3((n + 63) / 64, 3), 256, 0, stream>>>(x, T1a, T1b, (const float4*)vvT1, A, B, ela, era, n);
  k_gat_h1<128><<<nwb, 256, 0, stream>>>(rowptr, esrc, A, ela, era, b1a, B, b1b, C, n);

  // layer 2: hid=128 -> out=64 (grid.y = {0,ext})
  k_gemm2t<128, 64, 1><<<dim3((n + 31) / 32, 2), 256, 0, stream>>>(C, T2a, T2b, (const float4*)vvT2, A, B, ela, era, n);
  k_gat_h1<64><<<nwb, 256, 0, stream>>>(rowptr, esrc, A, ela, era, b2a, B, b2b, D2, n);

  // dh = chain_pass(h2)
  k_chainpass64<<<nwb, 256, 0, stream>>>(D2, E2, n);

  // MH layer: out=64 -> 4 heads x 64 (grid.y = {0..3,ext})
  k_gemm2t<64, 256, 4><<<dim3((n + 63) / 64, 5), 256, 0, stream>>>(E2, Tma, Tmb, (const float4*)vvTm, A, B, ela, era, n);
  k_gat_mh<<<nwb, 256, 0, stream>>>(rowptr, esrc, A, ela, era, bma, B, bmb, C, n);

  // ds = chain_pass(hm) -> staged directly in d_out
  k_chainpass_mh<<<nwb, 256, 0, stream>>>(C, dsout, n);

  // res = cumsum(ds, axis=0), in-place in d_out
  k_chunk_sum<<<nb, 256, 0, stream>>>(dsout, csum, n, ch);
  k_scan_chunks_par<<<256, 512, 0, stream>>>(csum, nb);
  k_apply_scan<<<nb, 256, 0, stream>>>(dsout, csum, n, ch);
}